// Round 3
// baseline (788.337 us; speedup 1.0000x reference)
//
#include <hip/hip_runtime.h>
#include <hip/hip_fp16.h>
#include <cstdint>

// Shapes (hard-coded): B=4, Cx=512, Cy=256, M=64, H=W=64, N=4096
constexpr int N_ = 4096;
constexpr float CNT = 16384.f;  // B*N reduction count for BN stats

typedef __attribute__((ext_vector_type(8))) _Float16 half8;
typedef __attribute__((ext_vector_type(4))) float f32x4;
union fragh { half8 h8; int i4[4]; };

__device__ inline int pkh(float a, float b) {
  union { __half2 h; int i; } u;
  u.h = __float22half2_rn(float2{a, b});
  return u.i;
}

// Stats layout (floats): group g in {0:s1,1:x1,2:y1,3:s2,4:x2,5:y2}:
//   sum at g*128+c, sumsq at g*128+64+c (c<64). f_up: sum 768+c, sumsq 1280+c.
//
// Workspace aliasing (stream-ordered, verified):
//   Wt1 (k-major stage-1 weights, 80K floats)  -> u region    (first written by convup)
//   Wt2' + bias (folded stage-2, 12.5K floats) -> fout region (first written by attn)
//   wut (k-major f_up weights, 32K floats)     -> z1s region  (dead after conv2)

// ---------------- prep1: transpose stage-1 weights to k-major [K][64] --------------
__global__ __launch_bounds__(256) void prep1_k(const float* __restrict__ ws1,
                                               const float* __restrict__ wx1,
                                               const float* __restrict__ wy1,
                                               float* __restrict__ wt1) {
  int e = blockIdx.x * 256 + threadIdx.x;  // 0..81919, write-coalesced
  if (e < 32768) {
    int k = e >> 6, o = e & 63;
    wt1[e] = ws1[o * 512 + k];
  } else if (e < 65536) {
    int e2 = e - 32768;
    int k = e2 >> 6, o = e2 & 63;
    wt1[e] = wx1[o * 512 + k];
  } else {
    int e3 = e - 65536;
    int k = e3 >> 6, o = e3 & 63;
    wt1[e] = wy1[o * 256 + k];
  }
}

// ---------------- prep2: fold BN1 into stage-2 weights; k-major + bias -------------
// z2 = w2 . (z1*sc + sh) = (w2*sc) . z1 + (w2 . sh)
__global__ __launch_bounds__(256) void prep2_k(
    const float* __restrict__ ws2, const float* __restrict__ wx2,
    const float* __restrict__ wy2,
    const float* __restrict__ gs1, const float* __restrict__ bs1,
    const float* __restrict__ gx1, const float* __restrict__ bx1,
    const float* __restrict__ gy1, const float* __restrict__ by1,
    const float* __restrict__ stats, float* __restrict__ wt2) {
  const int branch = blockIdx.x;
  const int t = threadIdx.x;
  const float* W = branch == 0 ? ws2 : (branch == 1 ? wx2 : wy2);
  const float* g1 = branch == 0 ? gs1 : (branch == 1 ? gx1 : gy1);
  const float* b1 = branch == 0 ? bs1 : (branch == 1 ? bx1 : by1);
  const float* stin = stats + branch * 128;
  float* outW = wt2 + branch * 4096;
  float* outB = wt2 + 12288 + branch * 64;

#pragma unroll
  for (int i = 0; i < 16; ++i) {
    int e = i * 256 + t;
    int k = e >> 6, o = e & 63;
    float mean = stin[k] * (1.f / CNT);
    float var = stin[64 + k] * (1.f / CNT) - mean * mean;
    float sc = g1[k] * rsqrtf(var + 1e-5f);
    outW[e] = W[o * 64 + k] * sc;
  }
  if (t < 64) {
    float s = 0.f;
    for (int k = 0; k < 64; ++k) {
      float mean = stin[k] * (1.f / CNT);
      float var = stin[64 + k] * (1.f / CNT) - mean * mean;
      float sc = g1[k] * rsqrtf(var + 1e-5f);
      float sh = b1[k] - mean * sc;
      s += W[t * 64 + k] * sh;
    }
    outB[t] = s;
  }
}

// ---------------- prep_up: transpose f_up weights to k-major [64][512] -------------
__global__ __launch_bounds__(256) void prepu_k(const float* __restrict__ wu,
                                               float* __restrict__ wut) {
  int e = blockIdx.x * 256 + threadIdx.x;  // 0..32767, write-coalesced
  int k = e >> 9, o = e & 511;
  wut[e] = wu[o * 64 + k];
}

// ---------------- stage-1 convs: weights-in-SGPR streaming GEMM --------------------
// Wave w owns channels w*16..w*16+15; per k: 16 uniform scalar weight loads
// (s_load_dwordx16 from k-major Wt) + 1 coalesced per-lane A load + 16 v_fmac with
// SGPR src. No LDS, no barriers. 768 blocks = 3/CU = 12 waves/CU.
__global__ __launch_bounds__(256) void conv1_k(
    const float* __restrict__ x, const float* __restrict__ y,
    const float* __restrict__ wt1,
    float* __restrict__ z1s, float* __restrict__ z1x, float* __restrict__ z1y,
    float* __restrict__ stats) {
  const int t = threadIdx.x;
  const int lane = t & 63;
  const int wave = __builtin_amdgcn_readfirstlane(t >> 6);
  const int slice = blockIdx.x;  // 0..255
  const int b = slice >> 6;
  const int n0 = (slice & 63) * 64;
  const int branch = blockIdx.y;  // 0:s 1:x 2:y
  const float* A = branch == 2 ? y : x;
  const float* Wt = wt1 + (branch == 0 ? 0 : (branch == 1 ? 32768 : 65536));
  float* out = branch == 0 ? z1s : (branch == 1 ? z1x : z1y);
  const int K = branch == 2 ? 256 : 512;
  float* st = stats + branch * 128;
  const int o0 = wave * 16;

  float acc[16];
#pragma unroll
  for (int i = 0; i < 16; ++i) acc[i] = 0.f;

  const float* Ap = A + (size_t)b * K * N_ + n0 + lane;
#pragma unroll 1
  for (int k0 = 0; k0 < K; k0 += 8) {
    float a[8];
#pragma unroll
    for (int j = 0; j < 8; ++j) a[j] = Ap[(size_t)(k0 + j) * N_];
#pragma unroll
    for (int j = 0; j < 8; ++j) {
      const float* wk = Wt + (k0 + j) * 64 + o0;  // wave-uniform -> SGPR
#pragma unroll
      for (int i = 0; i < 16; ++i) acc[i] = fmaf(wk[i], a[j], acc[i]);
    }
  }
  float* Cb = out + ((size_t)b * 64 + o0) * N_ + n0 + lane;
#pragma unroll
  for (int i = 0; i < 16; ++i) Cb[(size_t)i * N_] = acc[i];
#pragma unroll
  for (int i = 0; i < 16; ++i) {
    float s = acc[i];
    float q = acc[i] * acc[i];
#pragma unroll
    for (int d = 1; d < 64; d <<= 1) { s += __shfl_xor(s, d); q += __shfl_xor(q, d); }
    if (lane == 0) { atomicAdd(&st[o0 + i], s); atomicAdd(&st[64 + o0 + i], q); }
  }
}

// ---------------- stage-2 convs: same streaming GEMM, folded BN1 + bias ------------
__global__ __launch_bounds__(256) void conv2_k(
    const float* __restrict__ z1s, const float* __restrict__ z1x,
    const float* __restrict__ z1y, const float* __restrict__ wt2,
    float* __restrict__ z2s, float* __restrict__ z2x, float* __restrict__ z2y,
    float* __restrict__ stats) {
  const int t = threadIdx.x;
  const int lane = t & 63;
  const int wave = __builtin_amdgcn_readfirstlane(t >> 6);
  const int slice = blockIdx.x;
  const int b = slice >> 6;
  const int n0 = (slice & 63) * 64;
  const int branch = blockIdx.y;
  const float* A = branch == 0 ? z1s : (branch == 1 ? z1x : z1y);
  const float* Wt = wt2 + branch * 4096;
  const float* bias = wt2 + 12288 + branch * 64;
  float* out = branch == 0 ? z2s : (branch == 1 ? z2x : z2y);
  float* st = stats + (3 + branch) * 128;
  const int o0 = wave * 16;

  float acc[16];
#pragma unroll
  for (int i = 0; i < 16; ++i) acc[i] = bias[o0 + i];

  const float* Ap = A + (size_t)b * 64 * N_ + n0 + lane;
#pragma unroll 1
  for (int k0 = 0; k0 < 64; k0 += 8) {
    float a[8];
#pragma unroll
    for (int j = 0; j < 8; ++j) a[j] = Ap[(size_t)(k0 + j) * N_];
#pragma unroll
    for (int j = 0; j < 8; ++j) {
      const float* wk = Wt + (k0 + j) * 64 + o0;
#pragma unroll
      for (int i = 0; i < 16; ++i) acc[i] = fmaf(wk[i], a[j], acc[i]);
    }
  }
  float* Cb = out + ((size_t)b * 64 + o0) * N_ + n0 + lane;
#pragma unroll
  for (int i = 0; i < 16; ++i) Cb[(size_t)i * N_] = acc[i];
#pragma unroll
  for (int i = 0; i < 16; ++i) {
    float s = acc[i];
    float q = acc[i] * acc[i];
#pragma unroll
    for (int d = 1; d < 64; d <<= 1) { s += __shfl_xor(s, d); q += __shfl_xor(q, d); }
    if (lane == 0) { atomicAdd(&st[o0 + i], s); atomicAdd(&st[64 + o0 + i], q); }
  }
}

// ---------------- pack Q/K/V to fp16 with inline stage-2 BN ------------------------
// K and V written in exact MFMA fragment order (see round-2 notes): every K/V access
// in the attention K-loop is one fully-coalesced dwordx4.
__global__ __launch_bounds__(256) void pack_k(
    const float* __restrict__ z2s, const float* __restrict__ z2x,
    const float* __restrict__ z2y,
    const float* __restrict__ gs2, const float* __restrict__ bs2,
    const float* __restrict__ gx2, const float* __restrict__ bx2,
    const float* __restrict__ gy2, const float* __restrict__ by2,
    int* __restrict__ Qh, int* __restrict__ Kf, int* __restrict__ Vf,
    const float* __restrict__ stats) {
  const int job = blockIdx.z;  // 0: Q<-x2, 1: K<-y2, 2: V<-s2
  const int idx = blockIdx.x * 256 + threadIdx.x;  // 0..524287
  const float* z2 = job == 0 ? z2x : (job == 1 ? z2y : z2s);
  const float* g2 = job == 0 ? gx2 : (job == 1 ? gy2 : gs2);
  const float* b2 = job == 0 ? bx2 : (job == 1 ? by2 : bs2);
  const float* st = stats + (job == 0 ? 4 : (job == 1 ? 5 : 3)) * 128;
  int* outp = job == 0 ? Qh : (job == 1 ? Kf : Vf);

  auto snorm = [&](int c, float& s, float& h) {
    float mean = st[c] * (1.f / CNT);
    float var = st[64 + c] * (1.f / CNT) - mean * mean;
    float r = rsqrtf(var + 1e-5f);
    s = g2[c] * r;
    h = b2[c] - mean * s;
  };
  if (job == 0) {
    int n = idx & 4095, c = (idx >> 12) & 31, b = idx >> 17;
    float s0, h0, s1, h1;
    snorm(2 * c, s0, h0);
    snorm(2 * c + 1, s1, h1);
    float v0 = z2[((size_t)b * 64 + 2 * c) * N_ + n] * s0 + h0;
    float v1 = z2[((size_t)b * 64 + 2 * c + 1) * N_ + n] * s1 + h1;
    outp[idx] = pkh(v0, v1);
  } else if (job == 1) {
    int n = idx & 4095, c = (idx >> 12) & 31, b = idx >> 17;
    float s0, h0, s1, h1;
    snorm(2 * c, s0, h0);
    snorm(2 * c + 1, s1, h1);
    float v0 = z2[((size_t)b * 64 + 2 * c) * N_ + n] * s0 + h0;
    float v1 = z2[((size_t)b * 64 + 2 * c + 1) * N_ + n] * s1 + h1;
    int t16 = n >> 4, la = n & 15, g = c >> 4, quad = (c & 15) >> 2, jj = c & 3;
    outp[(((b * 256 + t16) * 2 + g) * 64 + quad * 16 + la) * 4 + jj] = pkh(v0, v1);
  } else {
    int k = idx & 2047, ch = (idx >> 11) & 63, b = idx >> 17;
    float s0, h0;
    snorm(ch, s0, h0);
    float2 v = *(const float2*)&z2[((size_t)b * 64 + ch) * N_ + 2 * k];
    int kb = k >> 4, p = k & 15, quad = p >> 2, w = p & 3, mt = ch >> 4, la = ch & 15;
    outp[(((b * 128 + kb) * 4 + mt) * 64 + quad * 16 + la) * 4 + w] =
        pkh(v.x * s0 + h0, v.y * s0 + h0);
  }
}

// ---------------- MFMA fp16 flash attention (unchanged, validated round 2) ---------
__global__ __launch_bounds__(256, 4) void attn_k(const int* __restrict__ Qh,
                                                 const int* __restrict__ Kf,
                                                 const int* __restrict__ Vf,
                                                 float* __restrict__ fout) {
  const int tid = threadIdx.x;
  const int lane = tid & 63;
  const int wid = tid >> 6;
  const int la = lane & 15;
  const int quad = lane >> 4;
  const int b = blockIdx.x & 3;
  const int qbase = (blockIdx.x >> 2) * 16;
  const int* Qb = Qh + (size_t)b * 32 * N_;
  const int* Kb4 = Kf + (size_t)b * 131072;
  const int* Vb4 = Vf + (size_t)b * 131072;

  __shared__ union USm {
    int P16[4][16 * 20];
    struct { float O[4][16][69]; float M[4][16]; float L[4][16]; } e;
  } smu;
  int* myP = smu.P16[wid];

  fragh aq[2];
#pragma unroll
  for (int c = 0; c < 2; ++c)
#pragma unroll
    for (int j = 0; j < 4; ++j)
      aq[c].i4[j] = Qb[(size_t)(c * 16 + quad * 4 + j) * N_ + qbase + la];

  f32x4 o[4];
  float mrun = -3.0e38f, lrun = 0.f;
#pragma unroll
  for (int mt = 0; mt < 4; ++mt) o[mt] = f32x4{0.f, 0.f, 0.f, 0.f};

  const int jbeg = wid * (N_ / 4);
  const int jend = jbeg + N_ / 4;

  int4 ka[2][2], kb2[2][2];
#pragma unroll
  for (int nt = 0; nt < 2; ++nt)
#pragma unroll
    for (int g = 0; g < 2; ++g)
      ka[nt][g] = *(const int4*)&Kb4[((((jbeg >> 4) + nt) * 2 + g) * 64 + lane) * 4];

  auto body = [&](int j0, int4 (&kc)[2][2], int4 (&kn)[2][2]) {
    f32x4 s[2];
#pragma unroll
    for (int nt = 0; nt < 2; ++nt) {
      fragh k0, k1;
      k0.i4[0] = kc[nt][0].x; k0.i4[1] = kc[nt][0].y;
      k0.i4[2] = kc[nt][0].z; k0.i4[3] = kc[nt][0].w;
      k1.i4[0] = kc[nt][1].x; k1.i4[1] = kc[nt][1].y;
      k1.i4[2] = kc[nt][1].z; k1.i4[3] = kc[nt][1].w;
      f32x4 z = f32x4{0.f, 0.f, 0.f, 0.f};
      z = __builtin_amdgcn_mfma_f32_16x16x32_f16(k0.h8, aq[0].h8, z, 0, 0, 0);
      s[nt] = __builtin_amdgcn_mfma_f32_16x16x32_f16(k1.h8, aq[1].h8, z, 0, 0, 0);
    }
    int4 vv[4];
#pragma unroll
    for (int mt = 0; mt < 4; ++mt)
      vv[mt] = *(const int4*)&Vb4[(((j0 >> 5) * 4 + mt) * 64 + lane) * 4];
    const int nj = (j0 + 32 < jend) ? (j0 + 32) : jbeg;
#pragma unroll
    for (int nt = 0; nt < 2; ++nt)
#pragma unroll
      for (int g = 0; g < 2; ++g)
        kn[nt][g] = *(const int4*)&Kb4[((((nj >> 4) + nt) * 2 + g) * 64 + lane) * 4];
    float t0 = fmaxf(fmaxf(s[0][0], s[0][1]), fmaxf(s[0][2], s[0][3]));
    float t1 = fmaxf(fmaxf(s[1][0], s[1][1]), fmaxf(s[1][2], s[1][3]));
    float t = fmaxf(t0, t1);
    t = fmaxf(t, __shfl_xor(t, 16));
    t = fmaxf(t, __shfl_xor(t, 32));
    float mnew = fmaxf(mrun, t);
    float alpha = __expf(mrun - mnew);
    float p[2][4];
    float ps = 0.f;
#pragma unroll
    for (int nt = 0; nt < 2; ++nt)
#pragma unroll
      for (int r = 0; r < 4; ++r) {
        p[nt][r] = __expf(s[nt][r] - mnew);
        ps += p[nt][r];
      }
    ps += __shfl_xor(ps, 16);
    ps += __shfl_xor(ps, 32);
    lrun = lrun * alpha + ps;
    mrun = mnew;
#pragma unroll
    for (int nt = 0; nt < 2; ++nt) {
      myP[(nt * 8 + quad * 2 + 0) * 20 + la] = pkh(p[nt][0], p[nt][1]);
      myP[(nt * 8 + quad * 2 + 1) * 20 + la] = pkh(p[nt][2], p[nt][3]);
    }
    __asm__ __volatile__("s_waitcnt lgkmcnt(0)" ::: "memory");
    fragh pb;
#pragma unroll
    for (int j = 0; j < 4; ++j) pb.i4[j] = myP[(quad * 4 + j) * 20 + la];
#pragma unroll
    for (int mt = 0; mt < 4; ++mt) {
      o[mt][0] *= alpha; o[mt][1] *= alpha;
      o[mt][2] *= alpha; o[mt][3] *= alpha;
    }
#pragma unroll
    for (int mt = 0; mt < 4; ++mt) {
      fragh vb;
      vb.i4[0] = vv[mt].x; vb.i4[1] = vv[mt].y;
      vb.i4[2] = vv[mt].z; vb.i4[3] = vv[mt].w;
      o[mt] = __builtin_amdgcn_mfma_f32_16x16x32_f16(vb.h8, pb.h8, o[mt], 0, 0, 0);
    }
  };

#pragma unroll 1
  for (int j0 = jbeg; j0 < jend; j0 += 64) {
    body(j0, ka, kb2);
    body(j0 + 32, kb2, ka);
  }

  __syncthreads();
  if (quad == 0) {
    smu.e.M[wid][la] = mrun;
    smu.e.L[wid][la] = lrun;
  }
#pragma unroll
  for (int mt = 0; mt < 4; ++mt)
#pragma unroll
    for (int r = 0; r < 4; ++r) smu.e.O[wid][la][mt * 16 + quad * 4 + r] = o[mt][r];
  __syncthreads();

#pragma unroll
  for (int t = 0; t < 4; ++t) {
    int oidx = t * 256 + tid;
    int m = oidx >> 4;
    int q = oidx & 15;
    float m0 = fmaxf(fmaxf(smu.e.M[0][q], smu.e.M[1][q]),
                     fmaxf(smu.e.M[2][q], smu.e.M[3][q]));
    float num = 0.f, den = 0.f;
#pragma unroll
    for (int w = 0; w < 4; ++w) {
      float wgt = __expf(smu.e.M[w][q] - m0);
      num += wgt * smu.e.O[w][q][m];
      den += wgt * smu.e.L[w][q];
    }
    fout[((size_t)b * 64 + m) * N_ + qbase + q] = num / den;
  }
}

// ---------------- f_up conv (K=64, O=512): weights-in-SGPR streaming GEMM ----------
__global__ __launch_bounds__(256) void convup_k(const float* __restrict__ fout,
                                                const float* __restrict__ wut,
                                                float* __restrict__ u,
                                                float* __restrict__ stats) {
  const int t = threadIdx.x;
  const int lane = t & 63;
  const int wave = __builtin_amdgcn_readfirstlane(t >> 6);
  const int slice = blockIdx.x;  // 0..255
  const int b = slice >> 6;
  const int n0 = (slice & 63) * 64;
  const int o0 = blockIdx.y * 64 + wave * 16;

  float acc[16];
#pragma unroll
  for (int i = 0; i < 16; ++i) acc[i] = 0.f;

  const float* Ap = fout + (size_t)b * 64 * N_ + n0 + lane;
#pragma unroll 1
  for (int k0 = 0; k0 < 64; k0 += 8) {
    float a[8];
#pragma unroll
    for (int j = 0; j < 8; ++j) a[j] = Ap[(size_t)(k0 + j) * N_];
#pragma unroll
    for (int j = 0; j < 8; ++j) {
      const float* wk = wut + (k0 + j) * 512 + o0;  // wave-uniform -> SGPR
#pragma unroll
      for (int i = 0; i < 16; ++i) acc[i] = fmaf(wk[i], a[j], acc[i]);
    }
  }
  float* Cb = u + ((size_t)b * 512 + o0) * N_ + n0 + lane;
#pragma unroll
  for (int i = 0; i < 16; ++i) Cb[(size_t)i * N_] = acc[i];
#pragma unroll
  for (int i = 0; i < 16; ++i) {
    float s = acc[i];
    float q = acc[i] * acc[i];
#pragma unroll
    for (int d = 1; d < 64; d <<= 1) { s += __shfl_xor(s, d); q += __shfl_xor(q, d); }
    if (lane == 0) {
      atomicAdd(&stats[768 + o0 + i], s);
      atomicAdd(&stats[1280 + o0 + i], q);
    }
  }
}

// ---------------- residual + final BN ----------------------------------------------
__global__ __launch_bounds__(256) void final_k(const float* __restrict__ x,
                                               const float* __restrict__ u,
                                               const float* __restrict__ gu,
                                               const float* __restrict__ bu,
                                               const float* __restrict__ stats,
                                               float* __restrict__ out) {
  size_t idx = (size_t)blockIdx.x * 256 + threadIdx.x;
  int c = (int)((idx >> 12) & 511);
  float mean = stats[768 + c] * (1.f / CNT);
  float var = stats[1280 + c] * (1.f / CNT) - mean * mean;
  float r = rsqrtf(var + 1e-5f);
  float s = gu[c] * r;
  float sh = bu[c] - mean * s;
  out[idx] = x[idx] + u[idx] * s + sh;
}

extern "C" void kernel_launch(void* const* d_in, const int* in_sizes, int n_in,
                              void* d_out, int out_size, void* d_ws, size_t ws_size,
                              hipStream_t stream) {
  const float* x = (const float*)d_in[0];
  const float* y = (const float*)d_in[1];
  const float* ws1 = (const float*)d_in[2];
  const float* gs1 = (const float*)d_in[3];
  const float* bs1 = (const float*)d_in[4];
  const float* ws2 = (const float*)d_in[5];
  const float* gs2 = (const float*)d_in[6];
  const float* bs2 = (const float*)d_in[7];
  const float* wx1 = (const float*)d_in[8];
  const float* gx1 = (const float*)d_in[9];
  const float* bx1 = (const float*)d_in[10];
  const float* wx2 = (const float*)d_in[11];
  const float* gx2 = (const float*)d_in[12];
  const float* bx2 = (const float*)d_in[13];
  const float* wy1 = (const float*)d_in[14];
  const float* gy1 = (const float*)d_in[15];
  const float* by1 = (const float*)d_in[16];
  const float* wy2 = (const float*)d_in[17];
  const float* gy2 = (const float*)d_in[18];
  const float* by2 = (const float*)d_in[19];
  const float* wu = (const float*)d_in[20];
  const float* gu = (const float*)d_in[21];
  const float* bu = (const float*)d_in[22];
  float* out = (float*)d_out;

  float* w = (float*)d_ws;
  const size_t M1 = 1048576;
  float* z1s = w + 0 * M1;
  float* z1x = w + 1 * M1;
  float* z1y = w + 2 * M1;
  float* z2s = w + 3 * M1;
  float* z2x = w + 4 * M1;
  float* z2y = w + 5 * M1;
  float* fout = w + 6 * M1;
  float* u = w + 7 * M1;  // [4][512][4096] = 8 M floats
  int* Qh = (int*)(w + 15 * M1);
  int* Kf = Qh + 524288;
  int* Vf = Kf + 524288;
  float* stats = (float*)(Vf + 524288);
  // weight staging aliases (stream-ordered reuse, see header comment)
  float* wt1 = u;      // 81920 floats; dead before convup writes u
  float* wt2 = fout;   // 12480 floats; dead before attn writes fout
  float* wut = z1s;    // 32768 floats; written after conv2 consumed z1s

  hipMemsetAsync(stats, 0, 1792 * sizeof(float), stream);

  prep1_k<<<dim3(320), dim3(256), 0, stream>>>(ws1, wx1, wy1, wt1);
  conv1_k<<<dim3(256, 3), dim3(256), 0, stream>>>(x, y, wt1, z1s, z1x, z1y, stats);
  prep2_k<<<dim3(3), dim3(256), 0, stream>>>(ws2, wx2, wy2, gs1, bs1, gx1, bx1,
                                             gy1, by1, stats, wt2);
  conv2_k<<<dim3(256, 3), dim3(256), 0, stream>>>(z1s, z1x, z1y, wt2, z2s, z2x,
                                                  z2y, stats);
  prepu_k<<<dim3(128), dim3(256), 0, stream>>>(wu, wut);
  pack_k<<<dim3(2048, 1, 3), dim3(256), 0, stream>>>(z2s, z2x, z2y, gs2, bs2, gx2,
                                                     bx2, gy2, by2, Qh, Kf, Vf,
                                                     stats);
  attn_k<<<dim3(1024), dim3(256), 0, stream>>>(Qh, Kf, Vf, fout);
  convup_k<<<dim3(256, 8), dim3(256), 0, stream>>>(fout, wut, u, stats);
  final_k<<<dim3(32768), dim3(256), 0, stream>>>(x, u, gu, bu, stats, out);
}

// Round 4
// 502.662 us; speedup vs baseline: 1.5683x; 1.5683x over previous
//
#include <hip/hip_runtime.h>
#include <hip/hip_fp16.h>
#include <cstdint>

// Shapes (hard-coded): B=4, Cx=512, Cy=256, M=64, H=W=64, N=4096
constexpr int N_ = 4096;
constexpr float CNT = 16384.f;  // B*N reduction count for BN stats

typedef __attribute__((ext_vector_type(8))) _Float16 half8;
typedef __attribute__((ext_vector_type(4))) float f32x4;
union fragh { half8 h8; int i4[4]; };

__device__ inline int pkh(float a, float b) {
  union { __half2 h; int i; } u;
  u.h = __float22half2_rn(float2{a, b});
  return u.i;
}

// Stats layout (floats): group g in {0:s1,1:x1,2:y1,3:s2,4:x2,5:y2}:
//   sum at g*128+c, sumsq at g*128+64+c (c<64). f_up: sum 768+c, sumsq 1280+c.
//
// Workspace aliasing (stream-ordered, verified round 3):
//   wt1 (k-major stage-1 weights) -> u region    (u first written by convup)
//   wt2'(folded stage-2 + bias)   -> fout region (fout first written by attn)
//   wut (k-major f_up weights)    -> z1s region  (written by prepu AFTER conv2)

// ---------------- prep1: transpose stage-1 weights to k-major [K][64] --------------
__global__ __launch_bounds__(256) void prep1_k(const float* __restrict__ ws1,
                                               const float* __restrict__ wx1,
                                               const float* __restrict__ wy1,
                                               float* __restrict__ wt1) {
  int e = blockIdx.x * 256 + threadIdx.x;  // 0..81919, write-coalesced
  if (e < 32768) {
    int k = e >> 6, o = e & 63;
    wt1[e] = ws1[o * 512 + k];
  } else if (e < 65536) {
    int e2 = e - 32768;
    int k = e2 >> 6, o = e2 & 63;
    wt1[e] = wx1[o * 512 + k];
  } else {
    int e3 = e - 65536;
    int k = e3 >> 6, o = e3 & 63;
    wt1[e] = wy1[o * 256 + k];
  }
}

// ---------------- prep2: fold BN1 into stage-2 weights; k-major + bias -------------
// z2 = w2 . (z1*sc + sh) = (w2*sc) . z1 + (w2 . sh)
__global__ __launch_bounds__(256) void prep2_k(
    const float* __restrict__ ws2, const float* __restrict__ wx2,
    const float* __restrict__ wy2,
    const float* __restrict__ gs1, const float* __restrict__ bs1,
    const float* __restrict__ gx1, const float* __restrict__ bx1,
    const float* __restrict__ gy1, const float* __restrict__ by1,
    const float* __restrict__ stats, float* __restrict__ wt2) {
  const int branch = blockIdx.x;
  const int t = threadIdx.x;
  const float* W = branch == 0 ? ws2 : (branch == 1 ? wx2 : wy2);
  const float* g1 = branch == 0 ? gs1 : (branch == 1 ? gx1 : gy1);
  const float* b1 = branch == 0 ? bs1 : (branch == 1 ? bx1 : by1);
  const float* stin = stats + branch * 128;
  float* outW = wt2 + branch * 4096;
  float* outB = wt2 + 12288 + branch * 64;

#pragma unroll
  for (int i = 0; i < 16; ++i) {
    int e = i * 256 + t;
    int k = e >> 6, o = e & 63;
    float mean = stin[k] * (1.f / CNT);
    float var = stin[64 + k] * (1.f / CNT) - mean * mean;
    float sc = g1[k] * rsqrtf(var + 1e-5f);
    outW[e] = W[o * 64 + k] * sc;
  }
  if (t < 64) {
    float s = 0.f;
    for (int k = 0; k < 64; ++k) {
      float mean = stin[k] * (1.f / CNT);
      float var = stin[64 + k] * (1.f / CNT) - mean * mean;
      float sc = g1[k] * rsqrtf(var + 1e-5f);
      float sh = b1[k] - mean * sc;
      s += W[t * 64 + k] * sh;
    }
    outB[t] = s;
  }
}

// ---------------- prep_up: transpose f_up weights to k-major [64][512] -------------
__global__ __launch_bounds__(256) void prepu_k(const float* __restrict__ wu,
                                               float* __restrict__ wut) {
  int e = blockIdx.x * 256 + threadIdx.x;  // 0..32767, write-coalesced
  int k = e >> 9, o = e & 511;
  wut[e] = wu[o * 64 + k];
}

// =============== conv template: 64o x 64n tile, 4o x 4n/thread, ====================
// register double-buffered staging (T14): load tile k+1 to regs BEFORE computing
// tile k from LDS; vmcnt-wait lands at the LDS write after the barrier, so global
// latency hides under ~1500 cyc of compute. Broadcast-friendly LDS reads.
struct ConvTile {
  float2 ra[4];
  float4 rw[2];
};
__device__ inline void ct_loadA(ConvTile& c, const float* __restrict__ Ab, int k0,
                                int t) {
#pragma unroll
  for (int i = 0; i < 4; ++i)
    c.ra[i] = *(const float2*)&Ab[(size_t)(k0 + i * 8 + (t >> 5)) * N_ + (t & 31) * 2];
}
__device__ inline void ct_storeA(ConvTile& c, float (*sA)[66], int t) {
#pragma unroll
  for (int i = 0; i < 4; ++i)
    *(float2*)&sA[i * 8 + (t >> 5)][(t & 31) * 2] = c.ra[i];
}
// Wt is k-major with row stride `wpitch` (64 for M-convs, 512 for f_up), o0 = column
__device__ inline void ct_loadW(ConvTile& c, const float* __restrict__ Wt, int k0,
                                int wpitch, int o0, int t) {
  const float* p = Wt + (size_t)(k0 + (t >> 3)) * wpitch + o0 + (t & 7) * 8;
  c.rw[0] = *(const float4*)p;
  c.rw[1] = *(const float4*)(p + 4);
}
__device__ inline void ct_storeW(ConvTile& c, float (*sW)[68], int t) {
  *(float4*)&sW[t >> 3][(t & 7) * 8] = c.rw[0];
  *(float4*)&sW[t >> 3][(t & 7) * 8 + 4] = c.rw[1];
}

// ---------------- stage-1 convs ----------------------------------------------------
__global__ __launch_bounds__(256) void conv1_k(
    const float* __restrict__ x, const float* __restrict__ y,
    const float* __restrict__ wt1,
    float* __restrict__ z1s, float* __restrict__ z1x, float* __restrict__ z1y,
    float* __restrict__ stats) {
  const int t = threadIdx.x;
  const int slice = blockIdx.x;  // 0..255
  const int b = slice >> 6;
  const int n0 = (slice & 63) * 64;
  const int branch = blockIdx.y;  // 0:s 1:x 2:y
  const float* A = branch == 2 ? y : x;
  const float* Wt = wt1 + (branch == 0 ? 0 : (branch == 1 ? 32768 : 65536));
  float* out = branch == 0 ? z1s : (branch == 1 ? z1x : z1y);
  const int K = branch == 2 ? 256 : 512;
  float* st = stats + branch * 128;

  __shared__ float sA[32][66];
  __shared__ float sW[32][68];

  const int tn = (t & 15) * 4;
  const int to = (t >> 4) * 4;
  float acc[4][4];
#pragma unroll
  for (int i = 0; i < 4; ++i)
#pragma unroll
    for (int j = 0; j < 4; ++j) acc[i][j] = 0.f;

  const float* Ab = A + (size_t)b * K * N_ + n0;
  ConvTile ct;
  ct_loadA(ct, Ab, 0, t);
  ct_loadW(ct, Wt, 0, 64, 0, t);
  ct_storeA(ct, sA, t);
  ct_storeW(ct, sW, t);
  __syncthreads();
#pragma unroll 1
  for (int k0 = 0; k0 < K; k0 += 32) {
    const int nk = k0 + 32;
    if (nk < K) {
      ct_loadA(ct, Ab, nk, t);
      ct_loadW(ct, Wt, nk, 64, 0, t);
    }
#pragma unroll
    for (int k = 0; k < 32; ++k) {
      float4 a = *(const float4*)&sA[k][tn];
      float4 w = *(const float4*)&sW[k][to];
      float wv[4] = {w.x, w.y, w.z, w.w};
      float av[4] = {a.x, a.y, a.z, a.w};
#pragma unroll
      for (int i = 0; i < 4; ++i)
#pragma unroll
        for (int j = 0; j < 4; ++j) acc[i][j] = fmaf(wv[i], av[j], acc[i][j]);
    }
    __syncthreads();
    if (nk < K) {
      ct_storeA(ct, sA, t);
      ct_storeW(ct, sW, t);
    }
    __syncthreads();
  }
  float* Cb = out + (size_t)b * 64 * N_ + n0;
#pragma unroll
  for (int i = 0; i < 4; ++i) {
    float4 v = {acc[i][0], acc[i][1], acc[i][2], acc[i][3]};
    *(float4*)&Cb[(size_t)(to + i) * N_ + tn] = v;
  }
#pragma unroll
  for (int i = 0; i < 4; ++i) {
    float s = acc[i][0] + acc[i][1] + acc[i][2] + acc[i][3];
    float q = acc[i][0] * acc[i][0] + acc[i][1] * acc[i][1] +
              acc[i][2] * acc[i][2] + acc[i][3] * acc[i][3];
#pragma unroll
    for (int d = 1; d < 16; d <<= 1) { s += __shfl_xor(s, d); q += __shfl_xor(q, d); }
    if ((t & 15) == 0) { atomicAdd(&st[to + i], s); atomicAdd(&st[64 + to + i], q); }
  }
}

// ---------------- stage-2 convs (K=64), BN1 pre-folded into wt2 + bias -------------
__global__ __launch_bounds__(256) void conv2_k(
    const float* __restrict__ z1s, const float* __restrict__ z1x,
    const float* __restrict__ z1y, const float* __restrict__ wt2,
    float* __restrict__ z2s, float* __restrict__ z2x, float* __restrict__ z2y,
    float* __restrict__ stats) {
  const int t = threadIdx.x;
  const int slice = blockIdx.x;
  const int b = slice >> 6;
  const int n0 = (slice & 63) * 64;
  const int branch = blockIdx.y;
  const float* A = branch == 0 ? z1s : (branch == 1 ? z1x : z1y);
  const float* Wt = wt2 + branch * 4096;
  const float* bias = wt2 + 12288 + branch * 64;
  float* out = branch == 0 ? z2s : (branch == 1 ? z2x : z2y);
  float* st = stats + (3 + branch) * 128;

  __shared__ float sA[32][66];
  __shared__ float sW[32][68];

  const int tn = (t & 15) * 4;
  const int to = (t >> 4) * 4;
  float acc[4][4];
#pragma unroll
  for (int i = 0; i < 4; ++i) {
    float bi = bias[to + i];
#pragma unroll
    for (int j = 0; j < 4; ++j) acc[i][j] = bi;
  }

  const float* Ab = A + (size_t)b * 64 * N_ + n0;
  ConvTile ct;
  ct_loadA(ct, Ab, 0, t);
  ct_loadW(ct, Wt, 0, 64, 0, t);
  ct_storeA(ct, sA, t);
  ct_storeW(ct, sW, t);
  __syncthreads();
#pragma unroll 1
  for (int k0 = 0; k0 < 64; k0 += 32) {
    const int nk = k0 + 32;
    if (nk < 64) {
      ct_loadA(ct, Ab, nk, t);
      ct_loadW(ct, Wt, nk, 64, 0, t);
    }
#pragma unroll
    for (int k = 0; k < 32; ++k) {
      float4 a = *(const float4*)&sA[k][tn];
      float4 w = *(const float4*)&sW[k][to];
      float wv[4] = {w.x, w.y, w.z, w.w};
      float av[4] = {a.x, a.y, a.z, a.w};
#pragma unroll
      for (int i = 0; i < 4; ++i)
#pragma unroll
        for (int j = 0; j < 4; ++j) acc[i][j] = fmaf(wv[i], av[j], acc[i][j]);
    }
    __syncthreads();
    if (nk < 64) {
      ct_storeA(ct, sA, t);
      ct_storeW(ct, sW, t);
    }
    __syncthreads();
  }
  float* Cb = out + (size_t)b * 64 * N_ + n0;
#pragma unroll
  for (int i = 0; i < 4; ++i) {
    float4 v = {acc[i][0], acc[i][1], acc[i][2], acc[i][3]};
    *(float4*)&Cb[(size_t)(to + i) * N_ + tn] = v;
  }
#pragma unroll
  for (int i = 0; i < 4; ++i) {
    float s = acc[i][0] + acc[i][1] + acc[i][2] + acc[i][3];
    float q = acc[i][0] * acc[i][0] + acc[i][1] * acc[i][1] +
              acc[i][2] * acc[i][2] + acc[i][3] * acc[i][3];
#pragma unroll
    for (int d = 1; d < 16; d <<= 1) { s += __shfl_xor(s, d); q += __shfl_xor(q, d); }
    if ((t & 15) == 0) { atomicAdd(&st[to + i], s); atomicAdd(&st[64 + to + i], q); }
  }
}

// ---------------- pack Q/K/V to fp16 with inline stage-2 BN ------------------------
// K and V written in exact MFMA fragment order: every K/V access in the attention
// K-loop is one fully-coalesced dwordx4.
__global__ __launch_bounds__(256) void pack_k(
    const float* __restrict__ z2s, const float* __restrict__ z2x,
    const float* __restrict__ z2y,
    const float* __restrict__ gs2, const float* __restrict__ bs2,
    const float* __restrict__ gx2, const float* __restrict__ bx2,
    const float* __restrict__ gy2, const float* __restrict__ by2,
    int* __restrict__ Qh, int* __restrict__ Kf, int* __restrict__ Vf,
    const float* __restrict__ stats) {
  const int job = blockIdx.z;  // 0: Q<-x2, 1: K<-y2, 2: V<-s2
  const int idx = blockIdx.x * 256 + threadIdx.x;  // 0..524287
  const float* z2 = job == 0 ? z2x : (job == 1 ? z2y : z2s);
  const float* g2 = job == 0 ? gx2 : (job == 1 ? gy2 : gs2);
  const float* b2 = job == 0 ? bx2 : (job == 1 ? by2 : bs2);
  const float* st = stats + (job == 0 ? 4 : (job == 1 ? 5 : 3)) * 128;
  int* outp = job == 0 ? Qh : (job == 1 ? Kf : Vf);

  auto snorm = [&](int c, float& s, float& h) {
    float mean = st[c] * (1.f / CNT);
    float var = st[64 + c] * (1.f / CNT) - mean * mean;
    float r = rsqrtf(var + 1e-5f);
    s = g2[c] * r;
    h = b2[c] - mean * s;
  };
  if (job == 0) {
    int n = idx & 4095, c = (idx >> 12) & 31, b = idx >> 17;
    float s0, h0, s1, h1;
    snorm(2 * c, s0, h0);
    snorm(2 * c + 1, s1, h1);
    float v0 = z2[((size_t)b * 64 + 2 * c) * N_ + n] * s0 + h0;
    float v1 = z2[((size_t)b * 64 + 2 * c + 1) * N_ + n] * s1 + h1;
    outp[idx] = pkh(v0, v1);
  } else if (job == 1) {
    int n = idx & 4095, c = (idx >> 12) & 31, b = idx >> 17;
    float s0, h0, s1, h1;
    snorm(2 * c, s0, h0);
    snorm(2 * c + 1, s1, h1);
    float v0 = z2[((size_t)b * 64 + 2 * c) * N_ + n] * s0 + h0;
    float v1 = z2[((size_t)b * 64 + 2 * c + 1) * N_ + n] * s1 + h1;
    int t16 = n >> 4, la = n & 15, g = c >> 4, quad = (c & 15) >> 2, jj = c & 3;
    outp[(((b * 256 + t16) * 2 + g) * 64 + quad * 16 + la) * 4 + jj] = pkh(v0, v1);
  } else {
    int k = idx & 2047, ch = (idx >> 11) & 63, b = idx >> 17;
    float s0, h0;
    snorm(ch, s0, h0);
    float2 v = *(const float2*)&z2[((size_t)b * 64 + ch) * N_ + 2 * k];
    int kb = k >> 4, p = k & 15, quad = p >> 2, w = p & 3, mt = ch >> 4, la = ch & 15;
    outp[(((b * 128 + kb) * 4 + mt) * 64 + quad * 16 + la) * 4 + w] =
        pkh(v.x * s0 + h0, v.y * s0 + h0);
  }
}

// ---------------- MFMA fp16 flash attention (unchanged, validated round 2) ---------
__global__ __launch_bounds__(256, 4) void attn_k(const int* __restrict__ Qh,
                                                 const int* __restrict__ Kf,
                                                 const int* __restrict__ Vf,
                                                 float* __restrict__ fout) {
  const int tid = threadIdx.x;
  const int lane = tid & 63;
  const int wid = tid >> 6;
  const int la = lane & 15;
  const int quad = lane >> 4;
  const int b = blockIdx.x & 3;
  const int qbase = (blockIdx.x >> 2) * 16;
  const int* Qb = Qh + (size_t)b * 32 * N_;
  const int* Kb4 = Kf + (size_t)b * 131072;
  const int* Vb4 = Vf + (size_t)b * 131072;

  __shared__ union USm {
    int P16[4][16 * 20];
    struct { float O[4][16][69]; float M[4][16]; float L[4][16]; } e;
  } smu;
  int* myP = smu.P16[wid];

  fragh aq[2];
#pragma unroll
  for (int c = 0; c < 2; ++c)
#pragma unroll
    for (int j = 0; j < 4; ++j)
      aq[c].i4[j] = Qb[(size_t)(c * 16 + quad * 4 + j) * N_ + qbase + la];

  f32x4 o[4];
  float mrun = -3.0e38f, lrun = 0.f;
#pragma unroll
  for (int mt = 0; mt < 4; ++mt) o[mt] = f32x4{0.f, 0.f, 0.f, 0.f};

  const int jbeg = wid * (N_ / 4);
  const int jend = jbeg + N_ / 4;

  int4 ka[2][2], kb2[2][2];
#pragma unroll
  for (int nt = 0; nt < 2; ++nt)
#pragma unroll
    for (int g = 0; g < 2; ++g)
      ka[nt][g] = *(const int4*)&Kb4[((((jbeg >> 4) + nt) * 2 + g) * 64 + lane) * 4];

  auto body = [&](int j0, int4 (&kc)[2][2], int4 (&kn)[2][2]) {
    f32x4 s[2];
#pragma unroll
    for (int nt = 0; nt < 2; ++nt) {
      fragh k0, k1;
      k0.i4[0] = kc[nt][0].x; k0.i4[1] = kc[nt][0].y;
      k0.i4[2] = kc[nt][0].z; k0.i4[3] = kc[nt][0].w;
      k1.i4[0] = kc[nt][1].x; k1.i4[1] = kc[nt][1].y;
      k1.i4[2] = kc[nt][1].z; k1.i4[3] = kc[nt][1].w;
      f32x4 z = f32x4{0.f, 0.f, 0.f, 0.f};
      z = __builtin_amdgcn_mfma_f32_16x16x32_f16(k0.h8, aq[0].h8, z, 0, 0, 0);
      s[nt] = __builtin_amdgcn_mfma_f32_16x16x32_f16(k1.h8, aq[1].h8, z, 0, 0, 0);
    }
    int4 vv[4];
#pragma unroll
    for (int mt = 0; mt < 4; ++mt)
      vv[mt] = *(const int4*)&Vb4[(((j0 >> 5) * 4 + mt) * 64 + lane) * 4];
    const int nj = (j0 + 32 < jend) ? (j0 + 32) : jbeg;
#pragma unroll
    for (int nt = 0; nt < 2; ++nt)
#pragma unroll
      for (int g = 0; g < 2; ++g)
        kn[nt][g] = *(const int4*)&Kb4[((((nj >> 4) + nt) * 2 + g) * 64 + lane) * 4];
    float t0 = fmaxf(fmaxf(s[0][0], s[0][1]), fmaxf(s[0][2], s[0][3]));
    float t1 = fmaxf(fmaxf(s[1][0], s[1][1]), fmaxf(s[1][2], s[1][3]));
    float t = fmaxf(t0, t1);
    t = fmaxf(t, __shfl_xor(t, 16));
    t = fmaxf(t, __shfl_xor(t, 32));
    float mnew = fmaxf(mrun, t);
    float alpha = __expf(mrun - mnew);
    float p[2][4];
    float ps = 0.f;
#pragma unroll
    for (int nt = 0; nt < 2; ++nt)
#pragma unroll
      for (int r = 0; r < 4; ++r) {
        p[nt][r] = __expf(s[nt][r] - mnew);
        ps += p[nt][r];
      }
    ps += __shfl_xor(ps, 16);
    ps += __shfl_xor(ps, 32);
    lrun = lrun * alpha + ps;
    mrun = mnew;
#pragma unroll
    for (int nt = 0; nt < 2; ++nt) {
      myP[(nt * 8 + quad * 2 + 0) * 20 + la] = pkh(p[nt][0], p[nt][1]);
      myP[(nt * 8 + quad * 2 + 1) * 20 + la] = pkh(p[nt][2], p[nt][3]);
    }
    __asm__ __volatile__("s_waitcnt lgkmcnt(0)" ::: "memory");
    fragh pb;
#pragma unroll
    for (int j = 0; j < 4; ++j) pb.i4[j] = myP[(quad * 4 + j) * 20 + la];
#pragma unroll
    for (int mt = 0; mt < 4; ++mt) {
      o[mt][0] *= alpha; o[mt][1] *= alpha;
      o[mt][2] *= alpha; o[mt][3] *= alpha;
    }
#pragma unroll
    for (int mt = 0; mt < 4; ++mt) {
      fragh vb;
      vb.i4[0] = vv[mt].x; vb.i4[1] = vv[mt].y;
      vb.i4[2] = vv[mt].z; vb.i4[3] = vv[mt].w;
      o[mt] = __builtin_amdgcn_mfma_f32_16x16x32_f16(vb.h8, pb.h8, o[mt], 0, 0, 0);
    }
  };

#pragma unroll 1
  for (int j0 = jbeg; j0 < jend; j0 += 64) {
    body(j0, ka, kb2);
    body(j0 + 32, kb2, ka);
  }

  __syncthreads();
  if (quad == 0) {
    smu.e.M[wid][la] = mrun;
    smu.e.L[wid][la] = lrun;
  }
#pragma unroll
  for (int mt = 0; mt < 4; ++mt)
#pragma unroll
    for (int r = 0; r < 4; ++r) smu.e.O[wid][la][mt * 16 + quad * 4 + r] = o[mt][r];
  __syncthreads();

#pragma unroll
  for (int t = 0; t < 4; ++t) {
    int oidx = t * 256 + tid;
    int m = oidx >> 4;
    int q = oidx & 15;
    float m0 = fmaxf(fmaxf(smu.e.M[0][q], smu.e.M[1][q]),
                     fmaxf(smu.e.M[2][q], smu.e.M[3][q]));
    float num = 0.f, den = 0.f;
#pragma unroll
    for (int w = 0; w < 4; ++w) {
      float wgt = __expf(smu.e.M[w][q] - m0);
      num += wgt * smu.e.O[w][q][m];
      den += wgt * smu.e.L[w][q];
    }
    fout[((size_t)b * 64 + m) * N_ + qbase + q] = num / den;
  }
}

// ---------------- f_up conv (K=64, O=512) ------------------------------------------
__global__ __launch_bounds__(256) void convup_k(const float* __restrict__ fout,
                                                const float* __restrict__ wut,
                                                float* __restrict__ u,
                                                float* __restrict__ stats) {
  const int t = threadIdx.x;
  const int slice = blockIdx.x;  // 0..255
  const int b = slice >> 6;
  const int n0 = (slice & 63) * 64;
  const int o0 = blockIdx.y * 64;

  __shared__ float sA[32][66];
  __shared__ float sW[32][68];

  const int tn = (t & 15) * 4;
  const int to = (t >> 4) * 4;
  float acc[4][4];
#pragma unroll
  for (int i = 0; i < 4; ++i)
#pragma unroll
    for (int j = 0; j < 4; ++j) acc[i][j] = 0.f;

  const float* Ab = fout + (size_t)b * 64 * N_ + n0;
  ConvTile ct;
  ct_loadA(ct, Ab, 0, t);
  ct_loadW(ct, wut, 0, 512, o0, t);
  ct_storeA(ct, sA, t);
  ct_storeW(ct, sW, t);
  __syncthreads();
#pragma unroll 1
  for (int k0 = 0; k0 < 64; k0 += 32) {
    const int nk = k0 + 32;
    if (nk < 64) {
      ct_loadA(ct, Ab, nk, t);
      ct_loadW(ct, wut, nk, 512, o0, t);
    }
#pragma unroll
    for (int k = 0; k < 32; ++k) {
      float4 a = *(const float4*)&sA[k][tn];
      float4 w = *(const float4*)&sW[k][to];
      float wv[4] = {w.x, w.y, w.z, w.w};
      float av[4] = {a.x, a.y, a.z, a.w};
#pragma unroll
      for (int i = 0; i < 4; ++i)
#pragma unroll
        for (int j = 0; j < 4; ++j) acc[i][j] = fmaf(wv[i], av[j], acc[i][j]);
    }
    __syncthreads();
    if (nk < 64) {
      ct_storeA(ct, sA, t);
      ct_storeW(ct, sW, t);
    }
    __syncthreads();
  }
  float* Cb = u + ((size_t)b * 512 + o0) * N_ + n0;
#pragma unroll
  for (int i = 0; i < 4; ++i) {
    float4 v = {acc[i][0], acc[i][1], acc[i][2], acc[i][3]};
    *(float4*)&Cb[(size_t)(to + i) * N_ + tn] = v;
  }
#pragma unroll
  for (int i = 0; i < 4; ++i) {
    float s = acc[i][0] + acc[i][1] + acc[i][2] + acc[i][3];
    float q = acc[i][0] * acc[i][0] + acc[i][1] * acc[i][1] +
              acc[i][2] * acc[i][2] + acc[i][3] * acc[i][3];
#pragma unroll
    for (int d = 1; d < 16; d <<= 1) { s += __shfl_xor(s, d); q += __shfl_xor(q, d); }
    if ((t & 15) == 0) {
      atomicAdd(&stats[768 + o0 + to + i], s);
      atomicAdd(&stats[1280 + o0 + to + i], q);
    }
  }
}

// ---------------- residual + final BN ----------------------------------------------
__global__ __launch_bounds__(256) void final_k(const float* __restrict__ x,
                                               const float* __restrict__ u,
                                               const float* __restrict__ gu,
                                               const float* __restrict__ bu,
                                               const float* __restrict__ stats,
                                               float* __restrict__ out) {
  size_t idx = (size_t)blockIdx.x * 256 + threadIdx.x;
  int c = (int)((idx >> 12) & 511);
  float mean = stats[768 + c] * (1.f / CNT);
  float var = stats[1280 + c] * (1.f / CNT) - mean * mean;
  float r = rsqrtf(var + 1e-5f);
  float s = gu[c] * r;
  float sh = bu[c] - mean * s;
  out[idx] = x[idx] + u[idx] * s + sh;
}

extern "C" void kernel_launch(void* const* d_in, const int* in_sizes, int n_in,
                              void* d_out, int out_size, void* d_ws, size_t ws_size,
                              hipStream_t stream) {
  const float* x = (const float*)d_in[0];
  const float* y = (const float*)d_in[1];
  const float* ws1 = (const float*)d_in[2];
  const float* gs1 = (const float*)d_in[3];
  const float* bs1 = (const float*)d_in[4];
  const float* ws2 = (const float*)d_in[5];
  const float* gs2 = (const float*)d_in[6];
  const float* bs2 = (const float*)d_in[7];
  const float* wx1 = (const float*)d_in[8];
  const float* gx1 = (const float*)d_in[9];
  const float* bx1 = (const float*)d_in[10];
  const float* wx2 = (const float*)d_in[11];
  const float* gx2 = (const float*)d_in[12];
  const float* bx2 = (const float*)d_in[13];
  const float* wy1 = (const float*)d_in[14];
  const float* gy1 = (const float*)d_in[15];
  const float* by1 = (const float*)d_in[16];
  const float* wy2 = (const float*)d_in[17];
  const float* gy2 = (const float*)d_in[18];
  const float* by2 = (const float*)d_in[19];
  const float* wu = (const float*)d_in[20];
  const float* gu = (const float*)d_in[21];
  const float* bu = (const float*)d_in[22];
  float* out = (float*)d_out;

  float* w = (float*)d_ws;
  const size_t M1 = 1048576;
  float* z1s = w + 0 * M1;
  float* z1x = w + 1 * M1;
  float* z1y = w + 2 * M1;
  float* z2s = w + 3 * M1;
  float* z2x = w + 4 * M1;
  float* z2y = w + 5 * M1;
  float* fout = w + 6 * M1;
  float* u = w + 7 * M1;  // [4][512][4096] = 8 M floats
  int* Qh = (int*)(w + 15 * M1);
  int* Kf = Qh + 524288;
  int* Vf = Kf + 524288;
  float* stats = (float*)(Vf + 524288);
  // weight staging aliases (stream-ordered reuse, see header comment)
  float* wt1 = u;      // 81920 floats; dead before convup writes u
  float* wt2 = fout;   // 12480 floats; dead before attn writes fout
  float* wut = z1s;    // 32768 floats; written after conv2 consumed z1s

  hipMemsetAsync(stats, 0, 1792 * sizeof(float), stream);

  prep1_k<<<dim3(320), dim3(256), 0, stream>>>(ws1, wx1, wy1, wt1);
  conv1_k<<<dim3(256, 3), dim3(256), 0, stream>>>(x, y, wt1, z1s, z1x, z1y, stats);
  prep2_k<<<dim3(3), dim3(256), 0, stream>>>(ws2, wx2, wy2, gs1, bs1, gx1, bx1,
                                             gy1, by1, stats, wt2);
  conv2_k<<<dim3(256, 3), dim3(256), 0, stream>>>(z1s, z1x, z1y, wt2, z2s, z2x,
                                                  z2y, stats);
  prepu_k<<<dim3(128), dim3(256), 0, stream>>>(wu, wut);
  pack_k<<<dim3(2048, 1, 3), dim3(256), 0, stream>>>(z2s, z2x, z2y, gs2, bs2, gx2,
                                                     bx2, gy2, by2, Qh, Kf, Vf,
                                                     stats);
  attn_k<<<dim3(1024), dim3(256), 0, stream>>>(Qh, Kf, Vf, fout);
  convup_k<<<dim3(256, 8), dim3(256), 0, stream>>>(fout, wut, u, stats);
  final_k<<<dim3(32768), dim3(256), 0, stream>>>(x, u, gu, bu, stats, out);
}

// Round 5
// 378.565 us; speedup vs baseline: 2.0824x; 1.3278x over previous
//
#include <hip/hip_runtime.h>
#include <hip/hip_fp16.h>
#include <cstdint>

// Shapes (hard-coded): B=4, Cx=512, Cy=256, M=64, H=W=64, N=4096
constexpr int N_ = 4096;
constexpr float CNT = 16384.f;  // B*N reduction count for BN stats

typedef __attribute__((ext_vector_type(8))) _Float16 half8;
typedef __attribute__((ext_vector_type(4))) float f32x4;
union fragh { half8 h8; int i4[4]; };

__device__ inline int pkh(float a, float b) {
  union { __half2 h; int i; } u;
  u.h = __float22half2_rn(float2{a, b});
  return u.i;
}

// Stats layout (floats): group g in {0:s1,1:x1,2:y1,3:s2,4:x2,5:y2}:
//   sum at g*128+c, sumsq at g*128+64+c (c<64). f_up: sum 768+c, sumsq 1280+c.
//
// Workspace aliasing (stream-ordered, verified round 3):
//   wt1 (k-major stage-1 weights) -> u region    (u first written by convup)
//   wt2'(folded stage-2 + bias)   -> fout region (fout first written by attn)
//   wut (k-major f_up weights)    -> z1s region  (written by prepu AFTER conv2)

// ---------------- prep1: transpose stage-1 weights to k-major [K][64] --------------
__global__ __launch_bounds__(256) void prep1_k(const float* __restrict__ ws1,
                                               const float* __restrict__ wx1,
                                               const float* __restrict__ wy1,
                                               float* __restrict__ wt1) {
  int e = blockIdx.x * 256 + threadIdx.x;  // 0..81919, write-coalesced
  if (e < 32768) {
    int k = e >> 6, o = e & 63;
    wt1[e] = ws1[o * 512 + k];
  } else if (e < 65536) {
    int e2 = e - 32768;
    int k = e2 >> 6, o = e2 & 63;
    wt1[e] = wx1[o * 512 + k];
  } else {
    int e3 = e - 65536;
    int k = e3 >> 6, o = e3 & 63;
    wt1[e] = wy1[o * 256 + k];
  }
}

// ---------------- prep2: fold BN1 into stage-2 weights; k-major + bias -------------
// z2 = w2 . (z1*sc + sh) = (w2*sc) . z1 + (w2 . sh)
__global__ __launch_bounds__(256) void prep2_k(
    const float* __restrict__ ws2, const float* __restrict__ wx2,
    const float* __restrict__ wy2,
    const float* __restrict__ gs1, const float* __restrict__ bs1,
    const float* __restrict__ gx1, const float* __restrict__ bx1,
    const float* __restrict__ gy1, const float* __restrict__ by1,
    const float* __restrict__ stats, float* __restrict__ wt2) {
  const int branch = blockIdx.x;
  const int t = threadIdx.x;
  const float* W = branch == 0 ? ws2 : (branch == 1 ? wx2 : wy2);
  const float* g1 = branch == 0 ? gs1 : (branch == 1 ? gx1 : gy1);
  const float* b1 = branch == 0 ? bs1 : (branch == 1 ? bx1 : by1);
  const float* stin = stats + branch * 128;
  float* outW = wt2 + branch * 4096;
  float* outB = wt2 + 12288 + branch * 64;

#pragma unroll
  for (int i = 0; i < 16; ++i) {
    int e = i * 256 + t;
    int k = e >> 6, o = e & 63;
    float mean = stin[k] * (1.f / CNT);
    float var = stin[64 + k] * (1.f / CNT) - mean * mean;
    float sc = g1[k] * rsqrtf(var + 1e-5f);
    outW[e] = W[o * 64 + k] * sc;
  }
  if (t < 64) {
    float s = 0.f;
    for (int k = 0; k < 64; ++k) {
      float mean = stin[k] * (1.f / CNT);
      float var = stin[64 + k] * (1.f / CNT) - mean * mean;
      float sc = g1[k] * rsqrtf(var + 1e-5f);
      float sh = b1[k] - mean * sc;
      s += W[t * 64 + k] * sh;
    }
    outB[t] = s;
  }
}

// ---------------- prep_up: transpose f_up weights to k-major [64][512] -------------
__global__ __launch_bounds__(256) void prepu_k(const float* __restrict__ wu,
                                               float* __restrict__ wut) {
  int e = blockIdx.x * 256 + threadIdx.x;  // 0..32767, write-coalesced
  int k = e >> 9, o = e & 511;
  wut[e] = wu[o * 64 + k];
}

// =============== conv template: 64o x 256n tile, 256 threads, 8o x 8n/thread =======
// A-frag address depends only on t&31 (upper half-wave broadcasts lanes 0-31);
// W-frag address only on t>>5 (8 distinct -> broadcast). 64 FMA per 64 B LDS read
// -> VALU-bound. Register prefetch double-buffer; running pointers (no per-load
// 64-bit muls). KT=16.

// ---------------- stage-1 convs ----------------------------------------------------
__global__ __launch_bounds__(256) void conv1_k(
    const float* __restrict__ x, const float* __restrict__ y,
    const float* __restrict__ wt1,
    float* __restrict__ z1s, float* __restrict__ z1x, float* __restrict__ z1y,
    float* __restrict__ stats) {
  const int t = threadIdx.x;
  const int b = blockIdx.x >> 4;
  const int n0 = (blockIdx.x & 15) * 256;
  const int branch = blockIdx.y;  // 0:s 1:x 2:y
  const float* A = branch == 2 ? y : x;
  const float* Wt = wt1 + (branch == 0 ? 0 : (branch == 1 ? 32768 : 65536));
  float* out = branch == 0 ? z1s : (branch == 1 ? z1x : z1y);
  const int K = branch == 2 ? 256 : 512;
  float* st = stats + branch * 128;

  __shared__ float sA[16][260];
  __shared__ float sW[16][68];

  const int ng4 = (t & 31) * 4;
  const int og8 = (t >> 5) * 8;
  float acc[8][8];
#pragma unroll
  for (int i = 0; i < 8; ++i)
#pragma unroll
    for (int j = 0; j < 8; ++j) acc[i][j] = 0.f;

  const float* Ap = A + ((size_t)b * K + (t >> 6)) * N_ + n0 + (t & 63) * 4;
  const float* Wp = Wt + (size_t)(t >> 4) * 64 + (t & 15) * 4;
  const int arow = t >> 6, acol = (t & 63) * 4;
  const int wrow = t >> 4, wcol = (t & 15) * 4;

  float4 pa[4];
  float4 pw;
#pragma unroll
  for (int i = 0; i < 4; ++i) pa[i] = *(const float4*)(Ap + (size_t)(4 * i) * N_);
  pw = *(const float4*)Wp;
  Ap += (size_t)16 * N_;
  Wp += 16 * 64;
#pragma unroll
  for (int i = 0; i < 4; ++i) *(float4*)&sA[arow + 4 * i][acol] = pa[i];
  *(float4*)&sW[wrow][wcol] = pw;
  __syncthreads();

#pragma unroll 1
  for (int k0 = 0; k0 < K; k0 += 16) {
    const bool more = (k0 + 16) < K;
    if (more) {
#pragma unroll
      for (int i = 0; i < 4; ++i) pa[i] = *(const float4*)(Ap + (size_t)(4 * i) * N_);
      pw = *(const float4*)Wp;
      Ap += (size_t)16 * N_;
      Wp += 16 * 64;
    }
#pragma unroll
    for (int k = 0; k < 16; ++k) {
      float4 a0 = *(const float4*)&sA[k][ng4];
      float4 a1 = *(const float4*)&sA[k][128 + ng4];
      float4 w0 = *(const float4*)&sW[k][og8];
      float4 w1 = *(const float4*)&sW[k][og8 + 4];
      float av[8] = {a0.x, a0.y, a0.z, a0.w, a1.x, a1.y, a1.z, a1.w};
      float wv[8] = {w0.x, w0.y, w0.z, w0.w, w1.x, w1.y, w1.z, w1.w};
#pragma unroll
      for (int i = 0; i < 8; ++i)
#pragma unroll
        for (int j = 0; j < 8; ++j) acc[i][j] = fmaf(wv[i], av[j], acc[i][j]);
    }
    __syncthreads();
    if (more) {
#pragma unroll
      for (int i = 0; i < 4; ++i) *(float4*)&sA[arow + 4 * i][acol] = pa[i];
      *(float4*)&sW[wrow][wcol] = pw;
    }
    __syncthreads();
  }

  float* Cb = out + ((size_t)b * 64 + og8) * N_ + n0;
#pragma unroll
  for (int i = 0; i < 8; ++i) {
    float4 v0 = {acc[i][0], acc[i][1], acc[i][2], acc[i][3]};
    float4 v1 = {acc[i][4], acc[i][5], acc[i][6], acc[i][7]};
    *(float4*)&Cb[(size_t)i * N_ + ng4] = v0;
    *(float4*)&Cb[(size_t)i * N_ + 128 + ng4] = v1;
  }
#pragma unroll
  for (int i = 0; i < 8; ++i) {
    float s = 0.f, q = 0.f;
#pragma unroll
    for (int j = 0; j < 8; ++j) { s += acc[i][j]; q += acc[i][j] * acc[i][j]; }
#pragma unroll
    for (int d = 1; d < 32; d <<= 1) { s += __shfl_xor(s, d); q += __shfl_xor(q, d); }
    if ((t & 31) == 0) { atomicAdd(&st[og8 + i], s); atomicAdd(&st[64 + og8 + i], q); }
  }
}

// ---------------- stage-2 convs (K=64), BN1 pre-folded into wt2 + bias -------------
__global__ __launch_bounds__(256) void conv2_k(
    const float* __restrict__ z1s, const float* __restrict__ z1x,
    const float* __restrict__ z1y, const float* __restrict__ wt2,
    float* __restrict__ z2s, float* __restrict__ z2x, float* __restrict__ z2y,
    float* __restrict__ stats) {
  const int t = threadIdx.x;
  const int b = blockIdx.x >> 4;
  const int n0 = (blockIdx.x & 15) * 256;
  const int branch = blockIdx.y;
  const float* A = branch == 0 ? z1s : (branch == 1 ? z1x : z1y);
  const float* Wt = wt2 + branch * 4096;
  const float* bias = wt2 + 12288 + branch * 64;
  float* out = branch == 0 ? z2s : (branch == 1 ? z2x : z2y);
  float* st = stats + (3 + branch) * 128;

  __shared__ float sA[16][260];
  __shared__ float sW[16][68];

  const int ng4 = (t & 31) * 4;
  const int og8 = (t >> 5) * 8;
  float acc[8][8];
#pragma unroll
  for (int i = 0; i < 8; ++i) {
    float bi = bias[og8 + i];
#pragma unroll
    for (int j = 0; j < 8; ++j) acc[i][j] = bi;
  }

  const float* Ap = A + ((size_t)b * 64 + (t >> 6)) * N_ + n0 + (t & 63) * 4;
  const float* Wp = Wt + (size_t)(t >> 4) * 64 + (t & 15) * 4;
  const int arow = t >> 6, acol = (t & 63) * 4;
  const int wrow = t >> 4, wcol = (t & 15) * 4;

  float4 pa[4];
  float4 pw;
#pragma unroll
  for (int i = 0; i < 4; ++i) pa[i] = *(const float4*)(Ap + (size_t)(4 * i) * N_);
  pw = *(const float4*)Wp;
  Ap += (size_t)16 * N_;
  Wp += 16 * 64;
#pragma unroll
  for (int i = 0; i < 4; ++i) *(float4*)&sA[arow + 4 * i][acol] = pa[i];
  *(float4*)&sW[wrow][wcol] = pw;
  __syncthreads();

#pragma unroll 1
  for (int k0 = 0; k0 < 64; k0 += 16) {
    const bool more = (k0 + 16) < 64;
    if (more) {
#pragma unroll
      for (int i = 0; i < 4; ++i) pa[i] = *(const float4*)(Ap + (size_t)(4 * i) * N_);
      pw = *(const float4*)Wp;
      Ap += (size_t)16 * N_;
      Wp += 16 * 64;
    }
#pragma unroll
    for (int k = 0; k < 16; ++k) {
      float4 a0 = *(const float4*)&sA[k][ng4];
      float4 a1 = *(const float4*)&sA[k][128 + ng4];
      float4 w0 = *(const float4*)&sW[k][og8];
      float4 w1 = *(const float4*)&sW[k][og8 + 4];
      float av[8] = {a0.x, a0.y, a0.z, a0.w, a1.x, a1.y, a1.z, a1.w};
      float wv[8] = {w0.x, w0.y, w0.z, w0.w, w1.x, w1.y, w1.z, w1.w};
#pragma unroll
      for (int i = 0; i < 8; ++i)
#pragma unroll
        for (int j = 0; j < 8; ++j) acc[i][j] = fmaf(wv[i], av[j], acc[i][j]);
    }
    __syncthreads();
    if (more) {
#pragma unroll
      for (int i = 0; i < 4; ++i) *(float4*)&sA[arow + 4 * i][acol] = pa[i];
      *(float4*)&sW[wrow][wcol] = pw;
    }
    __syncthreads();
  }

  float* Cb = out + ((size_t)b * 64 + og8) * N_ + n0;
#pragma unroll
  for (int i = 0; i < 8; ++i) {
    float4 v0 = {acc[i][0], acc[i][1], acc[i][2], acc[i][3]};
    float4 v1 = {acc[i][4], acc[i][5], acc[i][6], acc[i][7]};
    *(float4*)&Cb[(size_t)i * N_ + ng4] = v0;
    *(float4*)&Cb[(size_t)i * N_ + 128 + ng4] = v1;
  }
#pragma unroll
  for (int i = 0; i < 8; ++i) {
    float s = 0.f, q = 0.f;
#pragma unroll
    for (int j = 0; j < 8; ++j) { s += acc[i][j]; q += acc[i][j] * acc[i][j]; }
#pragma unroll
    for (int d = 1; d < 32; d <<= 1) { s += __shfl_xor(s, d); q += __shfl_xor(q, d); }
    if ((t & 31) == 0) { atomicAdd(&st[og8 + i], s); atomicAdd(&st[64 + og8 + i], q); }
  }
}

// ---------------- pack Q/K/V to fp16 with inline stage-2 BN ------------------------
// K and V written in exact MFMA fragment order: every K/V access in the attention
// K-loop is one fully-coalesced dwordx4.
__global__ __launch_bounds__(256) void pack_k(
    const float* __restrict__ z2s, const float* __restrict__ z2x,
    const float* __restrict__ z2y,
    const float* __restrict__ gs2, const float* __restrict__ bs2,
    const float* __restrict__ gx2, const float* __restrict__ bx2,
    const float* __restrict__ gy2, const float* __restrict__ by2,
    int* __restrict__ Qh, int* __restrict__ Kf, int* __restrict__ Vf,
    const float* __restrict__ stats) {
  const int job = blockIdx.z;  // 0: Q<-x2, 1: K<-y2, 2: V<-s2
  const int idx = blockIdx.x * 256 + threadIdx.x;  // 0..524287
  const float* z2 = job == 0 ? z2x : (job == 1 ? z2y : z2s);
  const float* g2 = job == 0 ? gx2 : (job == 1 ? gy2 : gs2);
  const float* b2 = job == 0 ? bx2 : (job == 1 ? by2 : bs2);
  const float* st = stats + (job == 0 ? 4 : (job == 1 ? 5 : 3)) * 128;
  int* outp = job == 0 ? Qh : (job == 1 ? Kf : Vf);

  auto snorm = [&](int c, float& s, float& h) {
    float mean = st[c] * (1.f / CNT);
    float var = st[64 + c] * (1.f / CNT) - mean * mean;
    float r = rsqrtf(var + 1e-5f);
    s = g2[c] * r;
    h = b2[c] - mean * s;
  };
  if (job == 0) {
    int n = idx & 4095, c = (idx >> 12) & 31, b = idx >> 17;
    float s0, h0, s1, h1;
    snorm(2 * c, s0, h0);
    snorm(2 * c + 1, s1, h1);
    float v0 = z2[((size_t)b * 64 + 2 * c) * N_ + n] * s0 + h0;
    float v1 = z2[((size_t)b * 64 + 2 * c + 1) * N_ + n] * s1 + h1;
    outp[idx] = pkh(v0, v1);
  } else if (job == 1) {
    int n = idx & 4095, c = (idx >> 12) & 31, b = idx >> 17;
    float s0, h0, s1, h1;
    snorm(2 * c, s0, h0);
    snorm(2 * c + 1, s1, h1);
    float v0 = z2[((size_t)b * 64 + 2 * c) * N_ + n] * s0 + h0;
    float v1 = z2[((size_t)b * 64 + 2 * c + 1) * N_ + n] * s1 + h1;
    int t16 = n >> 4, la = n & 15, g = c >> 4, quad = (c & 15) >> 2, jj = c & 3;
    outp[(((b * 256 + t16) * 2 + g) * 64 + quad * 16 + la) * 4 + jj] = pkh(v0, v1);
  } else {
    int k = idx & 2047, ch = (idx >> 11) & 63, b = idx >> 17;
    float s0, h0;
    snorm(ch, s0, h0);
    float2 v = *(const float2*)&z2[((size_t)b * 64 + ch) * N_ + 2 * k];
    int kb = k >> 4, p = k & 15, quad = p >> 2, w = p & 3, mt = ch >> 4, la = ch & 15;
    outp[(((b * 128 + kb) * 4 + mt) * 64 + quad * 16 + la) * 4 + w] =
        pkh(v.x * s0 + h0, v.y * s0 + h0);
  }
}

// ---------------- MFMA fp16 flash attention (unchanged, validated round 2) ---------
__global__ __launch_bounds__(256, 4) void attn_k(const int* __restrict__ Qh,
                                                 const int* __restrict__ Kf,
                                                 const int* __restrict__ Vf,
                                                 float* __restrict__ fout) {
  const int tid = threadIdx.x;
  const int lane = tid & 63;
  const int wid = tid >> 6;
  const int la = lane & 15;
  const int quad = lane >> 4;
  const int b = blockIdx.x & 3;
  const int qbase = (blockIdx.x >> 2) * 16;
  const int* Qb = Qh + (size_t)b * 32 * N_;
  const int* Kb4 = Kf + (size_t)b * 131072;
  const int* Vb4 = Vf + (size_t)b * 131072;

  __shared__ union USm {
    int P16[4][16 * 20];
    struct { float O[4][16][69]; float M[4][16]; float L[4][16]; } e;
  } smu;
  int* myP = smu.P16[wid];

  fragh aq[2];
#pragma unroll
  for (int c = 0; c < 2; ++c)
#pragma unroll
    for (int j = 0; j < 4; ++j)
      aq[c].i4[j] = Qb[(size_t)(c * 16 + quad * 4 + j) * N_ + qbase + la];

  f32x4 o[4];
  float mrun = -3.0e38f, lrun = 0.f;
#pragma unroll
  for (int mt = 0; mt < 4; ++mt) o[mt] = f32x4{0.f, 0.f, 0.f, 0.f};

  const int jbeg = wid * (N_ / 4);
  const int jend = jbeg + N_ / 4;

  int4 ka[2][2], kb2[2][2];
#pragma unroll
  for (int nt = 0; nt < 2; ++nt)
#pragma unroll
    for (int g = 0; g < 2; ++g)
      ka[nt][g] = *(const int4*)&Kb4[((((jbeg >> 4) + nt) * 2 + g) * 64 + lane) * 4];

  auto body = [&](int j0, int4 (&kc)[2][2], int4 (&kn)[2][2]) {
    f32x4 s[2];
#pragma unroll
    for (int nt = 0; nt < 2; ++nt) {
      fragh k0, k1;
      k0.i4[0] = kc[nt][0].x; k0.i4[1] = kc[nt][0].y;
      k0.i4[2] = kc[nt][0].z; k0.i4[3] = kc[nt][0].w;
      k1.i4[0] = kc[nt][1].x; k1.i4[1] = kc[nt][1].y;
      k1.i4[2] = kc[nt][1].z; k1.i4[3] = kc[nt][1].w;
      f32x4 z = f32x4{0.f, 0.f, 0.f, 0.f};
      z = __builtin_amdgcn_mfma_f32_16x16x32_f16(k0.h8, aq[0].h8, z, 0, 0, 0);
      s[nt] = __builtin_amdgcn_mfma_f32_16x16x32_f16(k1.h8, aq[1].h8, z, 0, 0, 0);
    }
    int4 vv[4];
#pragma unroll
    for (int mt = 0; mt < 4; ++mt)
      vv[mt] = *(const int4*)&Vb4[(((j0 >> 5) * 4 + mt) * 64 + lane) * 4];
    const int nj = (j0 + 32 < jend) ? (j0 + 32) : jbeg;
#pragma unroll
    for (int nt = 0; nt < 2; ++nt)
#pragma unroll
      for (int g = 0; g < 2; ++g)
        kn[nt][g] = *(const int4*)&Kb4[((((nj >> 4) + nt) * 2 + g) * 64 + lane) * 4];
    float t0 = fmaxf(fmaxf(s[0][0], s[0][1]), fmaxf(s[0][2], s[0][3]));
    float t1 = fmaxf(fmaxf(s[1][0], s[1][1]), fmaxf(s[1][2], s[1][3]));
    float t = fmaxf(t0, t1);
    t = fmaxf(t, __shfl_xor(t, 16));
    t = fmaxf(t, __shfl_xor(t, 32));
    float mnew = fmaxf(mrun, t);
    float alpha = __expf(mrun - mnew);
    float p[2][4];
    float ps = 0.f;
#pragma unroll
    for (int nt = 0; nt < 2; ++nt)
#pragma unroll
      for (int r = 0; r < 4; ++r) {
        p[nt][r] = __expf(s[nt][r] - mnew);
        ps += p[nt][r];
      }
    ps += __shfl_xor(ps, 16);
    ps += __shfl_xor(ps, 32);
    lrun = lrun * alpha + ps;
    mrun = mnew;
#pragma unroll
    for (int nt = 0; nt < 2; ++nt) {
      myP[(nt * 8 + quad * 2 + 0) * 20 + la] = pkh(p[nt][0], p[nt][1]);
      myP[(nt * 8 + quad * 2 + 1) * 20 + la] = pkh(p[nt][2], p[nt][3]);
    }
    __asm__ __volatile__("s_waitcnt lgkmcnt(0)" ::: "memory");
    fragh pb;
#pragma unroll
    for (int j = 0; j < 4; ++j) pb.i4[j] = myP[(quad * 4 + j) * 20 + la];
#pragma unroll
    for (int mt = 0; mt < 4; ++mt) {
      o[mt][0] *= alpha; o[mt][1] *= alpha;
      o[mt][2] *= alpha; o[mt][3] *= alpha;
    }
#pragma unroll
    for (int mt = 0; mt < 4; ++mt) {
      fragh vb;
      vb.i4[0] = vv[mt].x; vb.i4[1] = vv[mt].y;
      vb.i4[2] = vv[mt].z; vb.i4[3] = vv[mt].w;
      o[mt] = __builtin_amdgcn_mfma_f32_16x16x32_f16(vb.h8, pb.h8, o[mt], 0, 0, 0);
    }
  };

#pragma unroll 1
  for (int j0 = jbeg; j0 < jend; j0 += 64) {
    body(j0, ka, kb2);
    body(j0 + 32, kb2, ka);
  }

  __syncthreads();
  if (quad == 0) {
    smu.e.M[wid][la] = mrun;
    smu.e.L[wid][la] = lrun;
  }
#pragma unroll
  for (int mt = 0; mt < 4; ++mt)
#pragma unroll
    for (int r = 0; r < 4; ++r) smu.e.O[wid][la][mt * 16 + quad * 4 + r] = o[mt][r];
  __syncthreads();

#pragma unroll
  for (int t = 0; t < 4; ++t) {
    int oidx = t * 256 + tid;
    int m = oidx >> 4;
    int q = oidx & 15;
    float m0 = fmaxf(fmaxf(smu.e.M[0][q], smu.e.M[1][q]),
                     fmaxf(smu.e.M[2][q], smu.e.M[3][q]));
    float num = 0.f, den = 0.f;
#pragma unroll
    for (int w = 0; w < 4; ++w) {
      float wgt = __expf(smu.e.M[w][q] - m0);
      num += wgt * smu.e.O[w][q][m];
      den += wgt * smu.e.L[w][q];
    }
    fout[((size_t)b * 64 + m) * N_ + qbase + q] = num / den;
  }
}

// ---------------- f_up conv (K=64, O=512) ------------------------------------------
__global__ __launch_bounds__(256) void convup_k(const float* __restrict__ fout,
                                                const float* __restrict__ wut,
                                                float* __restrict__ u,
                                                float* __restrict__ stats) {
  const int t = threadIdx.x;
  const int b = blockIdx.x >> 4;
  const int n0 = (blockIdx.x & 15) * 256;
  const int o0 = blockIdx.y * 64;

  __shared__ float sA[16][260];
  __shared__ float sW[16][68];

  const int ng4 = (t & 31) * 4;
  const int og8 = (t >> 5) * 8;
  float acc[8][8];
#pragma unroll
  for (int i = 0; i < 8; ++i)
#pragma unroll
    for (int j = 0; j < 8; ++j) acc[i][j] = 0.f;

  const float* Ap = fout + ((size_t)b * 64 + (t >> 6)) * N_ + n0 + (t & 63) * 4;
  const float* Wp = wut + (size_t)(t >> 4) * 512 + o0 + (t & 15) * 4;
  const int arow = t >> 6, acol = (t & 63) * 4;
  const int wrow = t >> 4, wcol = (t & 15) * 4;

  float4 pa[4];
  float4 pw;
#pragma unroll
  for (int i = 0; i < 4; ++i) pa[i] = *(const float4*)(Ap + (size_t)(4 * i) * N_);
  pw = *(const float4*)Wp;
  Ap += (size_t)16 * N_;
  Wp += 16 * 512;
#pragma unroll
  for (int i = 0; i < 4; ++i) *(float4*)&sA[arow + 4 * i][acol] = pa[i];
  *(float4*)&sW[wrow][wcol] = pw;
  __syncthreads();

#pragma unroll 1
  for (int k0 = 0; k0 < 64; k0 += 16) {
    const bool more = (k0 + 16) < 64;
    if (more) {
#pragma unroll
      for (int i = 0; i < 4; ++i) pa[i] = *(const float4*)(Ap + (size_t)(4 * i) * N_);
      pw = *(const float4*)Wp;
      Ap += (size_t)16 * N_;
      Wp += 16 * 512;
    }
#pragma unroll
    for (int k = 0; k < 16; ++k) {
      float4 a0 = *(const float4*)&sA[k][ng4];
      float4 a1 = *(const float4*)&sA[k][128 + ng4];
      float4 w0 = *(const float4*)&sW[k][og8];
      float4 w1 = *(const float4*)&sW[k][og8 + 4];
      float av[8] = {a0.x, a0.y, a0.z, a0.w, a1.x, a1.y, a1.z, a1.w};
      float wv[8] = {w0.x, w0.y, w0.z, w0.w, w1.x, w1.y, w1.z, w1.w};
#pragma unroll
      for (int i = 0; i < 8; ++i)
#pragma unroll
        for (int j = 0; j < 8; ++j) acc[i][j] = fmaf(wv[i], av[j], acc[i][j]);
    }
    __syncthreads();
    if (more) {
#pragma unroll
      for (int i = 0; i < 4; ++i) *(float4*)&sA[arow + 4 * i][acol] = pa[i];
      *(float4*)&sW[wrow][wcol] = pw;
    }
    __syncthreads();
  }

  float* Cb = u + ((size_t)b * 512 + o0 + og8) * N_ + n0;
#pragma unroll
  for (int i = 0; i < 8; ++i) {
    float4 v0 = {acc[i][0], acc[i][1], acc[i][2], acc[i][3]};
    float4 v1 = {acc[i][4], acc[i][5], acc[i][6], acc[i][7]};
    *(float4*)&Cb[(size_t)i * N_ + ng4] = v0;
    *(float4*)&Cb[(size_t)i * N_ + 128 + ng4] = v1;
  }
#pragma unroll
  for (int i = 0; i < 8; ++i) {
    float s = 0.f, q = 0.f;
#pragma unroll
    for (int j = 0; j < 8; ++j) { s += acc[i][j]; q += acc[i][j] * acc[i][j]; }
#pragma unroll
    for (int d = 1; d < 32; d <<= 1) { s += __shfl_xor(s, d); q += __shfl_xor(q, d); }
    if ((t & 31) == 0) {
      atomicAdd(&stats[768 + o0 + og8 + i], s);
      atomicAdd(&stats[1280 + o0 + og8 + i], q);
    }
  }
}

// ---------------- residual + final BN ----------------------------------------------
__global__ __launch_bounds__(256) void final_k(const float* __restrict__ x,
                                               const float* __restrict__ u,
                                               const float* __restrict__ gu,
                                               const float* __restrict__ bu,
                                               const float* __restrict__ stats,
                                               float* __restrict__ out) {
  size_t idx = (size_t)blockIdx.x * 256 + threadIdx.x;
  int c = (int)((idx >> 12) & 511);
  float mean = stats[768 + c] * (1.f / CNT);
  float var = stats[1280 + c] * (1.f / CNT) - mean * mean;
  float r = rsqrtf(var + 1e-5f);
  float s = gu[c] * r;
  float sh = bu[c] - mean * s;
  out[idx] = x[idx] + u[idx] * s + sh;
}

extern "C" void kernel_launch(void* const* d_in, const int* in_sizes, int n_in,
                              void* d_out, int out_size, void* d_ws, size_t ws_size,
                              hipStream_t stream) {
  const float* x = (const float*)d_in[0];
  const float* y = (const float*)d_in[1];
  const float* ws1 = (const float*)d_in[2];
  const float* gs1 = (const float*)d_in[3];
  const float* bs1 = (const float*)d_in[4];
  const float* ws2 = (const float*)d_in[5];
  const float* gs2 = (const float*)d_in[6];
  const float* bs2 = (const float*)d_in[7];
  const float* wx1 = (const float*)d_in[8];
  const float* gx1 = (const float*)d_in[9];
  const float* bx1 = (const float*)d_in[10];
  const float* wx2 = (const float*)d_in[11];
  const float* gx2 = (const float*)d_in[12];
  const float* bx2 = (const float*)d_in[13];
  const float* wy1 = (const float*)d_in[14];
  const float* gy1 = (const float*)d_in[15];
  const float* by1 = (const float*)d_in[16];
  const float* wy2 = (const float*)d_in[17];
  const float* gy2 = (const float*)d_in[18];
  const float* by2 = (const float*)d_in[19];
  const float* wu = (const float*)d_in[20];
  const float* gu = (const float*)d_in[21];
  const float* bu = (const float*)d_in[22];
  float* out = (float*)d_out;

  float* w = (float*)d_ws;
  const size_t M1 = 1048576;
  float* z1s = w + 0 * M1;
  float* z1x = w + 1 * M1;
  float* z1y = w + 2 * M1;
  float* z2s = w + 3 * M1;
  float* z2x = w + 4 * M1;
  float* z2y = w + 5 * M1;
  float* fout = w + 6 * M1;
  float* u = w + 7 * M1;  // [4][512][4096] = 8 M floats
  int* Qh = (int*)(w + 15 * M1);
  int* Kf = Qh + 524288;
  int* Vf = Kf + 524288;
  float* stats = (float*)(Vf + 524288);
  // weight staging aliases (stream-ordered reuse, see header comment)
  float* wt1 = u;      // 81920 floats; dead before convup writes u
  float* wt2 = fout;   // 12480 floats; dead before attn writes fout
  float* wut = z1s;    // 32768 floats; written after conv2 consumed z1s

  hipMemsetAsync(stats, 0, 1792 * sizeof(float), stream);

  prep1_k<<<dim3(320), dim3(256), 0, stream>>>(ws1, wx1, wy1, wt1);
  conv1_k<<<dim3(64, 3), dim3(256), 0, stream>>>(x, y, wt1, z1s, z1x, z1y, stats);
  prep2_k<<<dim3(3), dim3(256), 0, stream>>>(ws2, wx2, wy2, gs1, bs1, gx1, bx1,
                                             gy1, by1, stats, wt2);
  conv2_k<<<dim3(64, 3), dim3(256), 0, stream>>>(z1s, z1x, z1y, wt2, z2s, z2x,
                                                 z2y, stats);
  prepu_k<<<dim3(128), dim3(256), 0, stream>>>(wu, wut);
  pack_k<<<dim3(2048, 1, 3), dim3(256), 0, stream>>>(z2s, z2x, z2y, gs2, bs2, gx2,
                                                     bx2, gy2, by2, Qh, Kf, Vf,
                                                     stats);
  attn_k<<<dim3(1024), dim3(256), 0, stream>>>(Qh, Kf, Vf, fout);
  convup_k<<<dim3(64, 8), dim3(256), 0, stream>>>(fout, wut, u, stats);
  final_k<<<dim3(32768), dim3(256), 0, stream>>>(x, u, gu, bu, stats, out);
}

// Round 6
// 368.510 us; speedup vs baseline: 2.1393x; 1.0273x over previous
//
#include <hip/hip_runtime.h>
#include <hip/hip_fp16.h>
#include <cstdint>

// Shapes (hard-coded): B=4, Cx=512, Cy=256, M=64, H=W=64, N=4096
constexpr int N_ = 4096;
constexpr float CNT = 16384.f;  // B*N reduction count for BN stats

typedef __attribute__((ext_vector_type(8))) _Float16 half8;
typedef __attribute__((ext_vector_type(4))) float f32x4;
union fragh { half8 h8; int i4[4]; };

__device__ inline int pkh(float a, float b) {
  union { __half2 h; int i; } u;
  u.h = __float22half2_rn(float2{a, b});
  return u.i;
}
// split-fp16 (Markidis): h = rn(a,b) packed; l = rn(residuals) packed
__device__ inline void pk_hl(float a, float b, int& h, int& l) {
  __half ah = __float2half_rn(a), bh = __float2half_rn(b);
  union { __half2 v; int i; } u;
  u.v = __halves2half2(ah, bh);
  h = u.i;
  float ar = a - __half2float(ah), br = b - __half2float(bh);
  union { __half2 v; int i; } w2;
  w2.v = __float22half2_rn(float2{ar, br});
  l = w2.i;
}
__device__ inline float2 uph(int v) {
  union { __half2 h; int i; } u;
  u.i = v;
  return float2{__half2float(__low2half(u.h)), __half2float(__high2half(u.h))};
}

// Stats layout (floats): group g in {0:s1,1:x1,2:y1,3:s2,4:x2,5:y2}:
//   sum at g*128+c, sumsq at g*128+64+c (c<64). f_up: sum 768+c, sumsq 1280+c.
//
// Fragment layouts (validated by the passing attn kernel):
//  B-operand frag buffer (activations): int at
//    ((((bIdx*KT + kt)*256 + ntg)*64 + q*16 + la)*4 + jj)
//    holds fp16 pair (k = kt*32 + q*8 + 2jj, k+1) at col n = ntg*16 + la.
//    hi array then lo array (offset = total hi ints).
//  A-operand frag buffer (weights): int at (((ot*KT + kt)*64 + q*16+la)*4 + jj)
//    holds pair (k...) of W[o = ot*16 + la].
//
// Workspace aliasing (stream-ordered):
//  z1f  w[0..3M)   frag hi/lo per branch (1M ints each: hi .5M | lo .5M)
//  z2f  w[3..6M)   same; Afy aliases w[3..7M) (dead before conv2/attn write)
//  fout w[6..7M)   fp32 planar (attn -> convup)
//  u    w[7..15M)  fp32; Afx aliases it (dead before convup writes)
//  Qf/Kf/Vf at w+15M (0.5M ints each); stats after; weight packs + wut at tail

// ---------------- packA: x,y -> B-fragment hi/lo fp16 ------------------------------
__global__ __launch_bounds__(256) void packA_k(const float* __restrict__ x,
                                               const float* __restrict__ y,
                                               int* __restrict__ Afx,
                                               int* __restrict__ Afy) {
  const int job = blockIdx.y;
  if (job == 1 && blockIdx.x >= 2048) return;
  const int idx = blockIdx.x * 256 + threadIdx.x;
  const float* src = job ? y : x;
  int* dst = job ? Afy : Afx;
  const int KT = job ? 8 : 16;
  const int loOff = job ? 2097152 : 4194304;
  const int n = idx & 4095, q = (idx >> 12) & 3;
  const int kt = job ? ((idx >> 14) & 7) : ((idx >> 14) & 15);
  const int b = job ? (idx >> 17) : (idx >> 18);
  const float* sp = src + ((size_t)(b * (KT * 32) + kt * 32 + q * 8)) * N_ + n;
  float a[8];
#pragma unroll
  for (int j = 0; j < 8; ++j) a[j] = sp[(size_t)j * N_];
  int4 hi, lo;
  pk_hl(a[0], a[1], hi.x, lo.x);
  pk_hl(a[2], a[3], hi.y, lo.y);
  pk_hl(a[4], a[5], hi.z, lo.z);
  pk_hl(a[6], a[7], hi.w, lo.w);
  const int base = (((b * KT + kt) * 256 + (n >> 4)) * 64 + q * 16 + (n & 15)) * 4;
  *(int4*)&dst[base] = hi;
  *(int4*)&dst[loOff + base] = lo;
}

// ---------------- prep1: stage-1 weights -> A-fragment hi/lo -----------------------
__global__ __launch_bounds__(256) void prep1_k(const float* __restrict__ ws1,
                                               const float* __restrict__ wx1,
                                               const float* __restrict__ wy1,
                                               int* __restrict__ wt1f) {
  const int idx = blockIdx.x * 256 + threadIdx.x;  // 0..40959
  const float* W;
  int KT, K, hiBase, loOff, e;
  if (idx < 16384) { W = ws1; KT = 16; K = 512; hiBase = 0; loOff = 16384; e = idx; }
  else if (idx < 32768) { W = wx1; KT = 16; K = 512; hiBase = 32768; loOff = 16384; e = idx - 16384; }
  else { W = wy1; KT = 8; K = 256; hiBase = 65536; loOff = 8192; e = idx - 32768; }
  const int jj = e & 3, lane = (e >> 2) & 63;
  int kt, ot;
  if (KT == 16) { kt = (e >> 8) & 15; ot = e >> 12; } else { kt = (e >> 8) & 7; ot = e >> 11; }
  const int o = ot * 16 + (lane & 15);
  const int k = kt * 32 + (lane >> 4) * 8 + 2 * jj;
  int h, l;
  pk_hl(W[o * K + k], W[o * K + k + 1], h, l);
  wt1f[hiBase + e] = h;
  wt1f[hiBase + loOff + e] = l;
}

// ---------------- prep2: fold BN1 into stage-2 weights -> A-frag hi/lo + bias ------
__global__ __launch_bounds__(256) void prep2_k(
    const float* __restrict__ ws2, const float* __restrict__ wx2,
    const float* __restrict__ wy2,
    const float* __restrict__ gs1, const float* __restrict__ bs1,
    const float* __restrict__ gx1, const float* __restrict__ bx1,
    const float* __restrict__ gy1, const float* __restrict__ by1,
    const float* __restrict__ stats, int* __restrict__ wt2f,
    float* __restrict__ biasf) {
  const int branch = blockIdx.x;
  const int t = threadIdx.x;
  const float* W = branch == 0 ? ws2 : (branch == 1 ? wx2 : wy2);
  const float* g1 = branch == 0 ? gs1 : (branch == 1 ? gx1 : gy1);
  const float* b1 = branch == 0 ? bs1 : (branch == 1 ? bx1 : by1);
  const float* stin = stats + branch * 128;
  int* outW = wt2f + branch * 4096;

  auto scale = [&](int k) {
    float mean = stin[k] * (1.f / CNT);
    float var = stin[64 + k] * (1.f / CNT) - mean * mean;
    return g1[k] * rsqrtf(var + 1e-5f);
  };
#pragma unroll
  for (int i = 0; i < 8; ++i) {
    int e = i * 256 + t;
    int jj = e & 3, lane = (e >> 2) & 63, kt = (e >> 8) & 1, ot = e >> 9;
    int o = ot * 16 + (lane & 15);
    int k = kt * 32 + (lane >> 4) * 8 + 2 * jj;
    float w0 = W[o * 64 + k] * scale(k);
    float w1 = W[o * 64 + k + 1] * scale(k + 1);
    int h, l;
    pk_hl(w0, w1, h, l);
    outW[e] = h;
    outW[2048 + e] = l;
  }
  if (t < 64) {
    float s = 0.f;
    for (int k = 0; k < 64; ++k) {
      float mean = stin[k] * (1.f / CNT);
      float var = stin[64 + k] * (1.f / CNT) - mean * mean;
      float sc = g1[k] * rsqrtf(var + 1e-5f);
      float sh = b1[k] - mean * sc;
      s += W[t * 64 + k] * sh;
    }
    biasf[branch * 64 + t] = s;
  }
}

// ---------------- prep_up: transpose f_up weights to k-major [64][512] -------------
__global__ __launch_bounds__(256) void prepu_k(const float* __restrict__ wu,
                                               float* __restrict__ wut) {
  int e = blockIdx.x * 256 + threadIdx.x;
  int k = e >> 9, o = e & 511;
  wut[e] = wu[o * 64 + k];
}

// ---------------- stage-1 convs: split-fp16 MFMA GEMM, no LDS ----------------------
// Block 64o x 256n, 4 waves (each 64o x 64n = 4x4 C-tiles). 3 passes per K-step:
// Wh*Ah + Wh*Al + Wl*Ah (error ~2^-22). z1 emitted directly in B-frag hi/lo.
__global__ __launch_bounds__(256) void conv1_k(
    const int* __restrict__ Afx, const int* __restrict__ Afy,
    const int* __restrict__ wt1f, int* __restrict__ z1f,
    float* __restrict__ stats) {
  const int t = threadIdx.x;
  const int lane = t & 63;
  const int wv = t >> 6;
  const int la = lane & 15;
  const int quad = lane >> 4;
  const int b = blockIdx.x >> 4;
  const int ns = blockIdx.x & 15;
  const int branch = blockIdx.y;
  const int KT = branch == 2 ? 8 : 16;
  const int* Af = branch == 2 ? Afy : Afx;
  const int aLo = branch == 2 ? 2097152 : 4194304;
  const int* Wf = wt1f + (branch == 0 ? 0 : (branch == 1 ? 32768 : 65536));
  const int wLo = branch == 2 ? 8192 : 16384;
  float* st = stats + branch * 128;
  int* zb = z1f + branch * 1048576;

  f32x4 acc[4][4];
#pragma unroll
  for (int i = 0; i < 4; ++i)
#pragma unroll
    for (int j = 0; j < 4; ++j) acc[i][j] = f32x4{0.f, 0.f, 0.f, 0.f};

  const int ntg0 = ns * 16 + wv * 4;
#pragma unroll 1
  for (int kt = 0; kt < KT; ++kt) {
    fragh wh[4], wl[4], ah[4], al[4];
#pragma unroll
    for (int ot = 0; ot < 4; ++ot) {
      const int base = ((ot * KT + kt) * 64 + lane) * 4;
      *(int4*)wh[ot].i4 = *(const int4*)&Wf[base];
      *(int4*)wl[ot].i4 = *(const int4*)&Wf[wLo + base];
    }
#pragma unroll
    for (int nt = 0; nt < 4; ++nt) {
      const int base = (((b * KT + kt) * 256 + ntg0 + nt) * 64 + lane) * 4;
      *(int4*)ah[nt].i4 = *(const int4*)&Af[base];
      *(int4*)al[nt].i4 = *(const int4*)&Af[aLo + base];
    }
#pragma unroll
    for (int ot = 0; ot < 4; ++ot)
#pragma unroll
      for (int nt = 0; nt < 4; ++nt) {
        acc[ot][nt] = __builtin_amdgcn_mfma_f32_16x16x32_f16(wh[ot].h8, ah[nt].h8, acc[ot][nt], 0, 0, 0);
        acc[ot][nt] = __builtin_amdgcn_mfma_f32_16x16x32_f16(wh[ot].h8, al[nt].h8, acc[ot][nt], 0, 0, 0);
        acc[ot][nt] = __builtin_amdgcn_mfma_f32_16x16x32_f16(wl[ot].h8, ah[nt].h8, acc[ot][nt], 0, 0, 0);
      }
  }
  // z1 frag write: o = ot*16+quad*4+r, pairs (r0,r1),(r2,r3) are in-lane
#pragma unroll
  for (int ot = 0; ot < 4; ++ot) {
    const int ktz = ot >> 1;
    const int qz = (ot & 1) * 2 + (quad >> 1);
    const int jz = (quad & 1) * 2;
#pragma unroll
    for (int nt = 0; nt < 4; ++nt) {
      const int addr = (((b * 2 + ktz) * 256 + ntg0 + nt) * 64 + qz * 16 + la) * 4 + jz;
      int h0, l0, h1, l1;
      pk_hl(acc[ot][nt][0], acc[ot][nt][1], h0, l0);
      pk_hl(acc[ot][nt][2], acc[ot][nt][3], h1, l1);
      *(int2*)&zb[addr] = int2{h0, h1};
      *(int2*)&zb[524288 + addr] = int2{l0, l1};
    }
  }
#pragma unroll
  for (int ot = 0; ot < 4; ++ot)
#pragma unroll
    for (int r = 0; r < 4; ++r) {
      float s = acc[ot][0][r] + acc[ot][1][r] + acc[ot][2][r] + acc[ot][3][r];
      float q = acc[ot][0][r] * acc[ot][0][r] + acc[ot][1][r] * acc[ot][1][r] +
                acc[ot][2][r] * acc[ot][2][r] + acc[ot][3][r] * acc[ot][3][r];
#pragma unroll
      for (int d = 1; d < 16; d <<= 1) { s += __shfl_xor(s, d); q += __shfl_xor(q, d); }
      if (la == 0) {
        atomicAdd(&st[ot * 16 + quad * 4 + r], s);
        atomicAdd(&st[64 + ot * 16 + quad * 4 + r], q);
      }
    }
}

// ---------------- stage-2 convs: split-fp16 MFMA, BN1 pre-folded + bias ------------
__global__ __launch_bounds__(256) void conv2_k(
    const int* __restrict__ z1f, const int* __restrict__ wt2f,
    const float* __restrict__ biasf, int* __restrict__ z2f,
    float* __restrict__ stats) {
  const int t = threadIdx.x;
  const int lane = t & 63;
  const int wv = t >> 6;
  const int la = lane & 15;
  const int quad = lane >> 4;
  const int b = blockIdx.x >> 4;
  const int ns = blockIdx.x & 15;
  const int branch = blockIdx.y;
  const int* Af = z1f + branch * 1048576;
  const int* Wf = wt2f + branch * 4096;
  const float* bias = biasf + branch * 64;
  float* st = stats + (3 + branch) * 128;
  int* zb = z2f + branch * 1048576;

  f32x4 acc[4][4];
#pragma unroll
  for (int ot = 0; ot < 4; ++ot)
#pragma unroll
    for (int nt = 0; nt < 4; ++nt) {
#pragma unroll
      for (int r = 0; r < 4; ++r) acc[ot][nt][r] = bias[ot * 16 + quad * 4 + r];
    }

  const int ntg0 = ns * 16 + wv * 4;
#pragma unroll 1
  for (int kt = 0; kt < 2; ++kt) {
    fragh wh[4], wl[4], ah[4], al[4];
#pragma unroll
    for (int ot = 0; ot < 4; ++ot) {
      const int base = ((ot * 2 + kt) * 64 + lane) * 4;
      *(int4*)wh[ot].i4 = *(const int4*)&Wf[base];
      *(int4*)wl[ot].i4 = *(const int4*)&Wf[2048 + base];
    }
#pragma unroll
    for (int nt = 0; nt < 4; ++nt) {
      const int base = (((b * 2 + kt) * 256 + ntg0 + nt) * 64 + lane) * 4;
      *(int4*)ah[nt].i4 = *(const int4*)&Af[base];
      *(int4*)al[nt].i4 = *(const int4*)&Af[524288 + base];
    }
#pragma unroll
    for (int ot = 0; ot < 4; ++ot)
#pragma unroll
      for (int nt = 0; nt < 4; ++nt) {
        acc[ot][nt] = __builtin_amdgcn_mfma_f32_16x16x32_f16(wh[ot].h8, ah[nt].h8, acc[ot][nt], 0, 0, 0);
        acc[ot][nt] = __builtin_amdgcn_mfma_f32_16x16x32_f16(wh[ot].h8, al[nt].h8, acc[ot][nt], 0, 0, 0);
        acc[ot][nt] = __builtin_amdgcn_mfma_f32_16x16x32_f16(wl[ot].h8, ah[nt].h8, acc[ot][nt], 0, 0, 0);
      }
  }
#pragma unroll
  for (int ot = 0; ot < 4; ++ot) {
    const int ktz = ot >> 1;
    const int qz = (ot & 1) * 2 + (quad >> 1);
    const int jz = (quad & 1) * 2;
#pragma unroll
    for (int nt = 0; nt < 4; ++nt) {
      const int addr = (((b * 2 + ktz) * 256 + ntg0 + nt) * 64 + qz * 16 + la) * 4 + jz;
      int h0, l0, h1, l1;
      pk_hl(acc[ot][nt][0], acc[ot][nt][1], h0, l0);
      pk_hl(acc[ot][nt][2], acc[ot][nt][3], h1, l1);
      *(int2*)&zb[addr] = int2{h0, h1};
      *(int2*)&zb[524288 + addr] = int2{l0, l1};
    }
  }
#pragma unroll
  for (int ot = 0; ot < 4; ++ot)
#pragma unroll
    for (int r = 0; r < 4; ++r) {
      float s = acc[ot][0][r] + acc[ot][1][r] + acc[ot][2][r] + acc[ot][3][r];
      float q = acc[ot][0][r] * acc[ot][0][r] + acc[ot][1][r] * acc[ot][1][r] +
                acc[ot][2][r] * acc[ot][2][r] + acc[ot][3][r] * acc[ot][3][r];
#pragma unroll
      for (int d = 1; d < 16; d <<= 1) { s += __shfl_xor(s, d); q += __shfl_xor(q, d); }
      if (la == 0) {
        atomicAdd(&st[ot * 16 + quad * 4 + r], s);
        atomicAdd(&st[64 + ot * 16 + quad * 4 + r], q);
      }
    }
}

// ---------------- pack Q/K/V from frag-format z2 with inline BN2 -------------------
// Qf/Kf are identity-structure remaps of z2x/z2y frags (fully coalesced).
__global__ __launch_bounds__(256) void pack_k(
    const int* __restrict__ z2f,
    const float* __restrict__ gs2, const float* __restrict__ bs2,
    const float* __restrict__ gx2, const float* __restrict__ bx2,
    const float* __restrict__ gy2, const float* __restrict__ by2,
    int* __restrict__ Qf, int* __restrict__ Kf, int* __restrict__ Vf,
    const float* __restrict__ stats) {
  const int job = blockIdx.z;  // 0: Q<-x2, 1: K<-y2, 2: V<-s2
  const int idx = blockIdx.x * 256 + threadIdx.x;
  const float* g2 = job == 0 ? gx2 : (job == 1 ? gy2 : gs2);
  const float* b2 = job == 0 ? bx2 : (job == 1 ? by2 : bs2);
  const float* st = stats + (job == 0 ? 4 : (job == 1 ? 5 : 3)) * 128;

  auto snorm = [&](int c, float& s, float& h) {
    float mean = st[c] * (1.f / CNT);
    float var = st[64 + c] * (1.f / CNT) - mean * mean;
    float r = rsqrtf(var + 1e-5f);
    s = g2[c] * r;
    h = b2[c] - mean * s;
  };
  if (job < 2) {
    const int* zf = z2f + (job == 0 ? 1048576 : 2097152);
    int* outp = job == 0 ? Qf : Kf;
    int h = zf[idx], l = zf[524288 + idx];
    int jj = idx & 3, lane = (idx >> 2) & 63, q = lane >> 4;
    int kt = (idx >> 16) & 1;
    int c0 = 2 * (kt * 16 + q * 4 + jj);
    float s0, h0, s1, h1;
    snorm(c0, s0, h0);
    snorm(c0 + 1, s1, h1);
    float2 vh = uph(h), vl = uph(l);
    outp[idx] = pkh((vh.x + vl.x) * s0 + h0, (vh.y + vl.y) * s1 + h1);
  } else {
    int w_ = idx & 3, lane = (idx >> 2) & 63, la_v = lane & 15, q_v = lane >> 4;
    int mt = (idx >> 8) & 3, kb = (idx >> 10) & 127, b = idx >> 17;
    int ch = mt * 16 + la_v;
    int k = kb * 16 + q_v * 4 + w_;
    int n0 = 2 * k;
    int kp = ch >> 1, kt = kp >> 4, qz = (kp >> 2) & 3, jz = kp & 3, half = ch & 1;
    int a0 = (((b * 2 + kt) * 256 + (n0 >> 4)) * 64 + qz * 16 + (n0 & 15)) * 4 + jz;
    float2 h0v = uph(z2f[a0]), l0v = uph(z2f[524288 + a0]);
    float2 h1v = uph(z2f[a0 + 4]), l1v = uph(z2f[524288 + a0 + 4]);
    float v0 = half ? (h0v.y + l0v.y) : (h0v.x + l0v.x);
    float v1 = half ? (h1v.y + l1v.y) : (h1v.x + l1v.x);
    float s0, h0;
    snorm(ch, s0, h0);
    Vf[idx] = pkh(v0 * s0 + h0, v1 * s0 + h0);
  }
}

// ---------------- MFMA fp16 flash attention (body unchanged; Q/K frag addressing) --
__global__ __launch_bounds__(256, 4) void attn_k(const int* __restrict__ Qf,
                                                 const int* __restrict__ Kf,
                                                 const int* __restrict__ Vf,
                                                 float* __restrict__ fout) {
  const int tid = threadIdx.x;
  const int lane = tid & 63;
  const int wid = tid >> 6;
  const int la = lane & 15;
  const int quad = lane >> 4;
  const int b = blockIdx.x & 3;
  const int qbase = (blockIdx.x >> 2) * 16;
  const int* Qb = Qf + (size_t)b * 131072;
  const int* Kb4 = Kf + (size_t)b * 131072;
  const int* Vb4 = Vf + (size_t)b * 131072;

  __shared__ union USm {
    int P16[4][16 * 20];
    struct { float O[4][16][69]; float M[4][16]; float L[4][16]; } e;
  } smu;
  int* myP = smu.P16[wid];

  fragh aq[2];
#pragma unroll
  for (int c = 0; c < 2; ++c)
    *(int4*)aq[c].i4 =
        *(const int4*)&Qb[((c * 256 + (qbase >> 4)) * 64 + quad * 16 + la) * 4];

  f32x4 o[4];
  float mrun = -3.0e38f, lrun = 0.f;
#pragma unroll
  for (int mt = 0; mt < 4; ++mt) o[mt] = f32x4{0.f, 0.f, 0.f, 0.f};

  const int jbeg = wid * (N_ / 4);
  const int jend = jbeg + N_ / 4;

  int4 ka[2][2], kb2[2][2];
#pragma unroll
  for (int nt = 0; nt < 2; ++nt)
#pragma unroll
    for (int g = 0; g < 2; ++g)
      ka[nt][g] = *(const int4*)&Kb4[((g * 256 + (jbeg >> 4) + nt) * 64 + lane) * 4];

  auto body = [&](int j0, int4 (&kc)[2][2], int4 (&kn)[2][2]) {
    f32x4 s[2];
#pragma unroll
    for (int nt = 0; nt < 2; ++nt) {
      fragh k0, k1;
      k0.i4[0] = kc[nt][0].x; k0.i4[1] = kc[nt][0].y;
      k0.i4[2] = kc[nt][0].z; k0.i4[3] = kc[nt][0].w;
      k1.i4[0] = kc[nt][1].x; k1.i4[1] = kc[nt][1].y;
      k1.i4[2] = kc[nt][1].z; k1.i4[3] = kc[nt][1].w;
      f32x4 z = f32x4{0.f, 0.f, 0.f, 0.f};
      z = __builtin_amdgcn_mfma_f32_16x16x32_f16(k0.h8, aq[0].h8, z, 0, 0, 0);
      s[nt] = __builtin_amdgcn_mfma_f32_16x16x32_f16(k1.h8, aq[1].h8, z, 0, 0, 0);
    }
    int4 vv[4];
#pragma unroll
    for (int mt = 0; mt < 4; ++mt)
      vv[mt] = *(const int4*)&Vb4[(((j0 >> 5) * 4 + mt) * 64 + lane) * 4];
    const int nj = (j0 + 32 < jend) ? (j0 + 32) : jbeg;
#pragma unroll
    for (int nt = 0; nt < 2; ++nt)
#pragma unroll
      for (int g = 0; g < 2; ++g)
        kn[nt][g] = *(const int4*)&Kb4[((g * 256 + (nj >> 4) + nt) * 64 + lane) * 4];
    float t0 = fmaxf(fmaxf(s[0][0], s[0][1]), fmaxf(s[0][2], s[0][3]));
    float t1 = fmaxf(fmaxf(s[1][0], s[1][1]), fmaxf(s[1][2], s[1][3]));
    float t = fmaxf(t0, t1);
    t = fmaxf(t, __shfl_xor(t, 16));
    t = fmaxf(t, __shfl_xor(t, 32));
    float mnew = fmaxf(mrun, t);
    float alpha = __expf(mrun - mnew);
    float p[2][4];
    float ps = 0.f;
#pragma unroll
    for (int nt = 0; nt < 2; ++nt)
#pragma unroll
      for (int r = 0; r < 4; ++r) {
        p[nt][r] = __expf(s[nt][r] - mnew);
        ps += p[nt][r];
      }
    ps += __shfl_xor(ps, 16);
    ps += __shfl_xor(ps, 32);
    lrun = lrun * alpha + ps;
    mrun = mnew;
#pragma unroll
    for (int nt = 0; nt < 2; ++nt) {
      myP[(nt * 8 + quad * 2 + 0) * 20 + la] = pkh(p[nt][0], p[nt][1]);
      myP[(nt * 8 + quad * 2 + 1) * 20 + la] = pkh(p[nt][2], p[nt][3]);
    }
    __asm__ __volatile__("s_waitcnt lgkmcnt(0)" ::: "memory");
    fragh pb;
#pragma unroll
    for (int j = 0; j < 4; ++j) pb.i4[j] = myP[(quad * 4 + j) * 20 + la];
#pragma unroll
    for (int mt = 0; mt < 4; ++mt) {
      o[mt][0] *= alpha; o[mt][1] *= alpha;
      o[mt][2] *= alpha; o[mt][3] *= alpha;
    }
#pragma unroll
    for (int mt = 0; mt < 4; ++mt) {
      fragh vb;
      vb.i4[0] = vv[mt].x; vb.i4[1] = vv[mt].y;
      vb.i4[2] = vv[mt].z; vb.i4[3] = vv[mt].w;
      o[mt] = __builtin_amdgcn_mfma_f32_16x16x32_f16(vb.h8, pb.h8, o[mt], 0, 0, 0);
    }
  };

#pragma unroll 1
  for (int j0 = jbeg; j0 < jend; j0 += 64) {
    body(j0, ka, kb2);
    body(j0 + 32, kb2, ka);
  }

  __syncthreads();
  if (quad == 0) {
    smu.e.M[wid][la] = mrun;
    smu.e.L[wid][la] = lrun;
  }
#pragma unroll
  for (int mt = 0; mt < 4; ++mt)
#pragma unroll
    for (int r = 0; r < 4; ++r) smu.e.O[wid][la][mt * 16 + quad * 4 + r] = o[mt][r];
  __syncthreads();

#pragma unroll
  for (int t = 0; t < 4; ++t) {
    int oidx = t * 256 + tid;
    int m = oidx >> 4;
    int q = oidx & 15;
    float m0 = fmaxf(fmaxf(smu.e.M[0][q], smu.e.M[1][q]),
                     fmaxf(smu.e.M[2][q], smu.e.M[3][q]));
    float num = 0.f, den = 0.f;
#pragma unroll
    for (int w = 0; w < 4; ++w) {
      float wgt = __expf(smu.e.M[w][q] - m0);
      num += wgt * smu.e.O[w][q][m];
      den += wgt * smu.e.L[w][q];
    }
    fout[((size_t)b * 64 + m) * N_ + qbase + q] = num / den;
  }
}

// ---------------- f_up conv (K=64, O=512): FP32 SGEMM (unchanged from r5) ----------
__global__ __launch_bounds__(256) void convup_k(const float* __restrict__ fout,
                                                const float* __restrict__ wut,
                                                float* __restrict__ u,
                                                float* __restrict__ stats) {
  const int t = threadIdx.x;
  const int b = blockIdx.x >> 4;
  const int n0 = (blockIdx.x & 15) * 256;
  const int o0 = blockIdx.y * 64;

  __shared__ float sA[16][260];
  __shared__ float sW[16][68];

  const int ng4 = (t & 31) * 4;
  const int og8 = (t >> 5) * 8;
  float acc[8][8];
#pragma unroll
  for (int i = 0; i < 8; ++i)
#pragma unroll
    for (int j = 0; j < 8; ++j) acc[i][j] = 0.f;

  const float* Ap = fout + ((size_t)b * 64 + (t >> 6)) * N_ + n0 + (t & 63) * 4;
  const float* Wp = wut + (size_t)(t >> 4) * 512 + o0 + (t & 15) * 4;
  const int arow = t >> 6, acol = (t & 63) * 4;
  const int wrow = t >> 4, wcol = (t & 15) * 4;

  float4 pa[4];
  float4 pw;
#pragma unroll
  for (int i = 0; i < 4; ++i) pa[i] = *(const float4*)(Ap + (size_t)(4 * i) * N_);
  pw = *(const float4*)Wp;
  Ap += (size_t)16 * N_;
  Wp += 16 * 512;
#pragma unroll
  for (int i = 0; i < 4; ++i) *(float4*)&sA[arow + 4 * i][acol] = pa[i];
  *(float4*)&sW[wrow][wcol] = pw;
  __syncthreads();

#pragma unroll 1
  for (int k0 = 0; k0 < 64; k0 += 16) {
    const bool more = (k0 + 16) < 64;
    if (more) {
#pragma unroll
      for (int i = 0; i < 4; ++i) pa[i] = *(const float4*)(Ap + (size_t)(4 * i) * N_);
      pw = *(const float4*)Wp;
      Ap += (size_t)16 * N_;
      Wp += 16 * 512;
    }
#pragma unroll
    for (int k = 0; k < 16; ++k) {
      float4 a0 = *(const float4*)&sA[k][ng4];
      float4 a1 = *(const float4*)&sA[k][128 + ng4];
      float4 w0 = *(const float4*)&sW[k][og8];
      float4 w1 = *(const float4*)&sW[k][og8 + 4];
      float av[8] = {a0.x, a0.y, a0.z, a0.w, a1.x, a1.y, a1.z, a1.w};
      float wv[8] = {w0.x, w0.y, w0.z, w0.w, w1.x, w1.y, w1.z, w1.w};
#pragma unroll
      for (int i = 0; i < 8; ++i)
#pragma unroll
        for (int j = 0; j < 8; ++j) acc[i][j] = fmaf(wv[i], av[j], acc[i][j]);
    }
    __syncthreads();
    if (more) {
#pragma unroll
      for (int i = 0; i < 4; ++i) *(float4*)&sA[arow + 4 * i][acol] = pa[i];
      *(float4*)&sW[wrow][wcol] = pw;
    }
    __syncthreads();
  }

  float* Cb = u + ((size_t)b * 512 + o0 + og8) * N_ + n0;
#pragma unroll
  for (int i = 0; i < 8; ++i) {
    float4 v0 = {acc[i][0], acc[i][1], acc[i][2], acc[i][3]};
    float4 v1 = {acc[i][4], acc[i][5], acc[i][6], acc[i][7]};
    *(float4*)&Cb[(size_t)i * N_ + ng4] = v0;
    *(float4*)&Cb[(size_t)i * N_ + 128 + ng4] = v1;
  }
#pragma unroll
  for (int i = 0; i < 8; ++i) {
    float s = 0.f, q = 0.f;
#pragma unroll
    for (int j = 0; j < 8; ++j) { s += acc[i][j]; q += acc[i][j] * acc[i][j]; }
#pragma unroll
    for (int d = 1; d < 32; d <<= 1) { s += __shfl_xor(s, d); q += __shfl_xor(q, d); }
    if ((t & 31) == 0) {
      atomicAdd(&stats[768 + o0 + og8 + i], s);
      atomicAdd(&stats[1280 + o0 + og8 + i], q);
    }
  }
}

// ---------------- residual + final BN ----------------------------------------------
__global__ __launch_bounds__(256) void final_k(const float* __restrict__ x,
                                               const float* __restrict__ u,
                                               const float* __restrict__ gu,
                                               const float* __restrict__ bu,
                                               const float* __restrict__ stats,
                                               float* __restrict__ out) {
  size_t idx = (size_t)blockIdx.x * 256 + threadIdx.x;
  int c = (int)((idx >> 12) & 511);
  float mean = stats[768 + c] * (1.f / CNT);
  float var = stats[1280 + c] * (1.f / CNT) - mean * mean;
  float r = rsqrtf(var + 1e-5f);
  float s = gu[c] * r;
  float sh = bu[c] - mean * s;
  out[idx] = x[idx] + u[idx] * s + sh;
}

extern "C" void kernel_launch(void* const* d_in, const int* in_sizes, int n_in,
                              void* d_out, int out_size, void* d_ws, size_t ws_size,
                              hipStream_t stream) {
  const float* x = (const float*)d_in[0];
  const float* y = (const float*)d_in[1];
  const float* ws1 = (const float*)d_in[2];
  const float* gs1 = (const float*)d_in[3];
  const float* bs1 = (const float*)d_in[4];
  const float* ws2 = (const float*)d_in[5];
  const float* gs2 = (const float*)d_in[6];
  const float* bs2 = (const float*)d_in[7];
  const float* wx1 = (const float*)d_in[8];
  const float* gx1 = (const float*)d_in[9];
  const float* bx1 = (const float*)d_in[10];
  const float* wx2 = (const float*)d_in[11];
  const float* gx2 = (const float*)d_in[12];
  const float* bx2 = (const float*)d_in[13];
  const float* wy1 = (const float*)d_in[14];
  const float* gy1 = (const float*)d_in[15];
  const float* by1 = (const float*)d_in[16];
  const float* wy2 = (const float*)d_in[17];
  const float* gy2 = (const float*)d_in[18];
  const float* by2 = (const float*)d_in[19];
  const float* wu = (const float*)d_in[20];
  const float* gu = (const float*)d_in[21];
  const float* bu = (const float*)d_in[22];
  float* out = (float*)d_out;

  float* w = (float*)d_ws;
  const size_t M1 = 1048576;
  int* z1f = (int*)w;                      // 3M ints: [branch][hi .5M | lo .5M]
  int* z2f = (int*)(w + 3 * M1);           // 3M ints
  float* fout = w + 6 * M1;                // 1M fp32
  float* u = w + 7 * M1;                   // 8M fp32
  int* Afx = (int*)u;                      // 8M ints (hi 4M | lo 4M); dead pre-convup
  int* Afy = (int*)(w + 3 * M1);           // 4M ints over z2f+fout; dead pre-conv2
  int* Qf = (int*)(w + 15 * M1);
  int* Kf = Qf + 524288;
  int* Vf = Kf + 524288;
  float* stats = (float*)(Vf + 524288);    // 1792 floats
  int* wt1f = (int*)(stats + 1792);        // 81920 ints
  int* wt2f = wt1f + 81920;                // 12288 ints
  float* biasf = (float*)(wt2f + 12288);   // 192 floats
  float* wut = biasf + 192;                // 32768 floats

  hipMemsetAsync(stats, 0, 1792 * sizeof(float), stream);

  prep1_k<<<dim3(160), dim3(256), 0, stream>>>(ws1, wx1, wy1, wt1f);
  packA_k<<<dim3(4096, 2), dim3(256), 0, stream>>>(x, y, Afx, Afy);
  conv1_k<<<dim3(64, 3), dim3(256), 0, stream>>>(Afx, Afy, wt1f, z1f, stats);
  prep2_k<<<dim3(3), dim3(256), 0, stream>>>(ws2, wx2, wy2, gs1, bs1, gx1, bx1,
                                             gy1, by1, stats, wt2f, biasf);
  conv2_k<<<dim3(64, 3), dim3(256), 0, stream>>>(z1f, wt2f, biasf, z2f, stats);
  prepu_k<<<dim3(128), dim3(256), 0, stream>>>(wu, wut);
  pack_k<<<dim3(2048, 1, 3), dim3(256), 0, stream>>>(z2f, gs2, bs2, gx2, bx2, gy2,
                                                     by2, Qf, Kf, Vf, stats);
  attn_k<<<dim3(1024), dim3(256), 0, stream>>>(Qf, Kf, Vf, fout);
  convup_k<<<dim3(64, 8), dim3(256), 0, stream>>>(fout, wut, u, stats);
  final_k<<<dim3(32768), dim3(256), 0, stream>>>(x, u, gu, bu, stats, out);
}